// Round 7
// baseline (1096.649 us; speedup 1.0000x reference)
//
#include <hip/hip_runtime.h>
#include <hip/hip_bf16.h>

// Problem constants (B=2, S=1024, E=1024, H=16, D=64)
#define S_LEN 1024
#define E_DIM 1024
#define NH 16
#define HD 64
#define M_ROWS 2048   // B*S
#define BH_CNT 32     // B*NH

static constexpr float LR_C = 0.01f;
static constexpr float SC_C = 0.125f;  // 1/sqrt(64)

typedef unsigned short ushort_t;
typedef __attribute__((ext_vector_type(8))) __bf16 bf16x8;
typedef __attribute__((ext_vector_type(4))) float f32x4;

static __device__ inline ushort_t f2bu(float f) {
  __hip_bfloat16 h = __float2bfloat16(f);
  return *(ushort_t*)&h;
}
static __device__ inline bf16x8 ldg8(const ushort_t* p) { return *(const bf16x8*)p; }

// ---------------- weight prep: bf16 cast + bf16 transpose, 64x64 tiles ----------------
__global__ __launch_bounds__(256) void prep_w(const float* __restrict__ W,
                                              ushort_t* __restrict__ Wb,
                                              ushort_t* __restrict__ WTb) {
  __shared__ float ts[64][65];
  int bx = blockIdx.x * 64, by = blockIdx.y * 64;
  int t = threadIdx.x;
  int rr = t >> 6, cc = t & 63;
  #pragma unroll
  for (int p = 0; p < 16; p++) {
    int r = p * 4 + rr;
    float v = W[(size_t)(by + r) * E_DIM + bx + cc];
    ts[r][cc] = v;
    Wb[(size_t)(by + r) * E_DIM + bx + cc] = f2bu(v);
  }
  __syncthreads();
  #pragma unroll
  for (int p = 0; p < 16; p++) {
    int r = p * 4 + rr;
    WTb[(size_t)(bx + r) * E_DIM + by + cc] = f2bu(ts[cc][r]);
  }
}

// ---------------- per-head transpose: X[token][E] (head h cols) -> Xt[bh][64][S] ----------------
__global__ __launch_bounds__(256) void tr_head(const ushort_t* __restrict__ s0,
                                               const ushort_t* __restrict__ s1,
                                               const ushort_t* __restrict__ s2,
                                               ushort_t* __restrict__ d0,
                                               ushort_t* __restrict__ d1,
                                               ushort_t* __restrict__ d2) {
  int z = blockIdx.z;
  const ushort_t* src = (z == 0) ? s0 : (z == 1) ? s1 : s2;
  ushort_t* dst = (z == 0) ? d0 : (z == 1) ? d1 : d2;
  int t0 = blockIdx.x * 64;
  int bh = blockIdx.y, b = bh >> 4, h = bh & 15;
  __shared__ ushort_t L[64][72];
  int tid = threadIdx.x;
  #pragma unroll
  for (int p = 0; p < 2; p++) {
    int lin = tid + 256 * p;
    int r = lin >> 3, c = (lin & 7) * 8;
    *(uint4*)&L[r][c] = *(const uint4*)(src + (size_t)(b * S_LEN + t0 + r) * E_DIM + h * HD + c);
  }
  __syncthreads();
  #pragma unroll
  for (int p = 0; p < 2; p++) {
    int lin = tid + 256 * p;
    int d = lin & 63, tc = (lin >> 6) * 8;
    ushort_t tmp[8];
    #pragma unroll
    for (int u = 0; u < 8; u++) tmp[u] = L[tc + u][d];
    *(uint4*)(dst + (size_t)(bh * HD + d) * S_LEN + t0 + tc) = *(uint4*)tmp;
  }
}

// ---------------- bf16 MFMA GEMM, pipelined dbuf: C[2048,1024] = A*B^T ----------------
// MODE 0: Cb_z = bf16(acc), z of 3 [QKV proj]; MODE 1: Cb0 = bf16(T-acc); MODE 2: Cf += alpha*acc, Cb0=bf16(Cf)
template <int MODE, int NSEG>
__global__ __launch_bounds__(256) void gemm_mf(
    const ushort_t* __restrict__ A0, const ushort_t* __restrict__ A1, const ushort_t* __restrict__ A2,
    const ushort_t* __restrict__ B0, const ushort_t* __restrict__ B1, const ushort_t* __restrict__ B2,
    float* __restrict__ Cf, const float* __restrict__ T,
    ushort_t* __restrict__ Cb0, ushort_t* __restrict__ Cb1, ushort_t* __restrict__ Cb2,
    float alpha) {
  const int K = 1024;
  __shared__ __bf16 As[2][64][40];
  __shared__ __bf16 Bs[2][128][40];
  int tid = threadIdx.x;
  int m0 = blockIdx.y * 64, n0 = blockIdx.x * 128;

  const ushort_t* Bsel = B0;
  ushort_t* Cbz = Cb0;
  if (MODE == 0) {
    int z = blockIdx.z;
    Bsel = (z == 0) ? B0 : (z == 1) ? B1 : B2;
    Cbz = (z == 0) ? Cb0 : (z == 1) ? Cb1 : Cb2;
  }

  int lane = tid & 63, wave = tid >> 6;
  int wrow = wave >> 1, wcol = wave & 1;
  int fr = lane & 15, q = lane >> 4;

  f32x4 acc[2][4] = {};
  int ar = tid >> 2, ac = (tid & 3) * 8;

  uint4 av, bv0, bv1;
  {
    const ushort_t* Bg = (MODE == 0) ? Bsel : B0;
    av = *(const uint4*)(A0 + (size_t)(m0 + ar) * K + ac);
    bv0 = *(const uint4*)(Bg + (size_t)(n0 + ar) * K + ac);
    bv1 = *(const uint4*)(Bg + (size_t)(n0 + 64 + ar) * K + ac);
  }
  *(uint4*)&As[0][ar][ac] = av;
  *(uint4*)&Bs[0][ar][ac] = bv0;
  *(uint4*)&Bs[0][64 + ar][ac] = bv1;
  __syncthreads();
  int rb = 0;
  const int TOT = NSEG * (K / 32);
  #pragma unroll 1
  for (int t = 0; t < TOT; t++) {
    if (t + 1 < TOT) {
      int tn = t + 1;
      int s = tn >> 5;                 // 32 iterations per K-segment
      int k0 = (tn & 31) * 32;
      const ushort_t* Aseg = (s == 0) ? A0 : (s == 1) ? A1 : A2;
      const ushort_t* Bseg = (MODE == 0) ? Bsel : ((s == 0) ? B0 : (s == 1) ? B1 : B2);
      av = *(const uint4*)(Aseg + (size_t)(m0 + ar) * K + k0 + ac);
      bv0 = *(const uint4*)(Bseg + (size_t)(n0 + ar) * K + k0 + ac);
      bv1 = *(const uint4*)(Bseg + (size_t)(n0 + 64 + ar) * K + k0 + ac);
    }
    bf16x8 a0 = *(const bf16x8*)&As[rb][wrow * 32 + fr][q * 8];
    bf16x8 a1 = *(const bf16x8*)&As[rb][wrow * 32 + 16 + fr][q * 8];
    bf16x8 b0 = *(const bf16x8*)&Bs[rb][wcol * 64 + fr][q * 8];
    bf16x8 b1 = *(const bf16x8*)&Bs[rb][wcol * 64 + 16 + fr][q * 8];
    bf16x8 b2 = *(const bf16x8*)&Bs[rb][wcol * 64 + 32 + fr][q * 8];
    bf16x8 b3 = *(const bf16x8*)&Bs[rb][wcol * 64 + 48 + fr][q * 8];
    acc[0][0] = __builtin_amdgcn_mfma_f32_16x16x32_bf16(a0, b0, acc[0][0], 0, 0, 0);
    acc[0][1] = __builtin_amdgcn_mfma_f32_16x16x32_bf16(a0, b1, acc[0][1], 0, 0, 0);
    acc[0][2] = __builtin_amdgcn_mfma_f32_16x16x32_bf16(a0, b2, acc[0][2], 0, 0, 0);
    acc[0][3] = __builtin_amdgcn_mfma_f32_16x16x32_bf16(a0, b3, acc[0][3], 0, 0, 0);
    acc[1][0] = __builtin_amdgcn_mfma_f32_16x16x32_bf16(a1, b0, acc[1][0], 0, 0, 0);
    acc[1][1] = __builtin_amdgcn_mfma_f32_16x16x32_bf16(a1, b1, acc[1][1], 0, 0, 0);
    acc[1][2] = __builtin_amdgcn_mfma_f32_16x16x32_bf16(a1, b2, acc[1][2], 0, 0, 0);
    acc[1][3] = __builtin_amdgcn_mfma_f32_16x16x32_bf16(a1, b3, acc[1][3], 0, 0, 0);
    if (t + 1 < TOT) {
      *(uint4*)&As[rb ^ 1][ar][ac] = av;
      *(uint4*)&Bs[rb ^ 1][ar][ac] = bv0;
      *(uint4*)&Bs[rb ^ 1][64 + ar][ac] = bv1;
      __syncthreads();
      rb ^= 1;
    }
  }

  #pragma unroll
  for (int mi = 0; mi < 2; mi++)
    #pragma unroll
    for (int ni = 0; ni < 4; ni++) {
      int col = n0 + wcol * 64 + ni * 16 + fr;
      int row0 = m0 + wrow * 32 + mi * 16 + q * 4;
      #pragma unroll
      for (int r = 0; r < 4; r++) {
        size_t idx = (size_t)(row0 + r) * E_DIM + col;
        float v = acc[mi][ni][r];
        if (MODE == 0) {
          Cbz[idx] = f2bu(v);
        } else if (MODE == 1) {
          Cb0[idx] = f2bu(T[idx] - v);
        } else {
          float nv = Cf[idx] + alpha * v;
          Cf[idx] = nv;
          Cb0[idx] = f2bu(nv);
        }
      }
    }
}

// ====================== MFMA attention, pipelined LDS staging ======================
// MFMA 16x16x32: A[m=lane&15][k=q*8+u], B[n=lane&15][k=q*8+u], C: col=lane&15, row=q*4+reg.
// Block: 64-row tile, 4 waves = 4 bands of 16. Staged tiles padded to 72 (2-way banks).

// ---- fused fwd: single-pass flash, online softmax; emits m, 1/l, g=O-Xs (bf16), Dv ----
__global__ __launch_bounds__(256) void fwd_fused(const ushort_t* __restrict__ Qg,
                                                 const ushort_t* __restrict__ Kg,
                                                 const ushort_t* __restrict__ Vt,
                                                 const float* __restrict__ Xs,
                                                 float* __restrict__ mbuf,
                                                 float* __restrict__ lbuf,
                                                 ushort_t* __restrict__ Gb,
                                                 float* __restrict__ Dv) {
  int it = 15 - blockIdx.x;
  int bh = blockIdx.y, b = bh >> 4, h = bh & 15;
  int tid = threadIdx.x, lane = tid & 63, wv = tid >> 6;
  int fr = lane & 15, q = lane >> 4;
  int i0 = it * 64, band = wv * 16;
  __shared__ ushort_t Kts[2][64][72];  // [j][d]
  __shared__ ushort_t Vts[2][64][72];  // [d][j]
  __shared__ ushort_t Ps[64][72];      // [i][j] wave-private bands

  int r0 = tid >> 3, c0 = (tid & 7) * 8;  // staging: rows r0, r0+32, 8 bf16 each

  const ushort_t* Qrow = Qg + (size_t)(b * S_LEN + i0 + band + fr) * E_DIM + h * HD;
  bf16x8 aq0 = ldg8(Qrow + q * 8);
  bf16x8 aq1 = ldg8(Qrow + 32 + q * 8);

  uint4 pk[2], pv[2];
  {
    pk[0] = *(const uint4*)(Kg + (size_t)(b * S_LEN + r0) * E_DIM + h * HD + c0);
    pk[1] = *(const uint4*)(Kg + (size_t)(b * S_LEN + r0 + 32) * E_DIM + h * HD + c0);
    pv[0] = *(const uint4*)(Vt + (size_t)(bh * HD + r0) * S_LEN + c0);
    pv[1] = *(const uint4*)(Vt + (size_t)(bh * HD + r0 + 32) * S_LEN + c0);
  }
  *(uint4*)&Kts[0][r0][c0] = pk[0];
  *(uint4*)&Kts[0][r0 + 32][c0] = pk[1];
  *(uint4*)&Vts[0][r0][c0] = pv[0];
  *(uint4*)&Vts[0][r0 + 32][c0] = pv[1];
  __syncthreads();
  int rb = 0;

  float m[4], l[4];
  #pragma unroll
  for (int r = 0; r < 4; r++) { m[r] = -1e30f; l[r] = 0.f; }
  f32x4 oacc[4] = {};

  #pragma unroll 1
  for (int jt = 0; jt <= it; jt++) {
    int j0 = jt * 64;
    if (jt < it) {
      int j0n = j0 + 64;
      pk[0] = *(const uint4*)(Kg + (size_t)(b * S_LEN + j0n + r0) * E_DIM + h * HD + c0);
      pk[1] = *(const uint4*)(Kg + (size_t)(b * S_LEN + j0n + r0 + 32) * E_DIM + h * HD + c0);
      pv[0] = *(const uint4*)(Vt + (size_t)(bh * HD + r0) * S_LEN + j0n + c0);
      pv[1] = *(const uint4*)(Vt + (size_t)(bh * HD + r0 + 32) * S_LEN + j0n + c0);
    }
    f32x4 sA[4];
    #pragma unroll
    for (int nc = 0; nc < 4; nc++) {
      bf16x8 bk0 = *(const bf16x8*)&Kts[rb][nc * 16 + fr][q * 8];
      bf16x8 bk1 = *(const bf16x8*)&Kts[rb][nc * 16 + fr][32 + q * 8];
      f32x4 z = {};
      z = __builtin_amdgcn_mfma_f32_16x16x32_bf16(aq0, bk0, z, 0, 0, 0);
      sA[nc] = __builtin_amdgcn_mfma_f32_16x16x32_bf16(aq1, bk1, z, 0, 0, 0);
    }
    float sv[4][4];
    #pragma unroll
    for (int nc = 0; nc < 4; nc++)
      #pragma unroll
      for (int r = 0; r < 4; r++) {
        int row = i0 + band + q * 4 + r;
        int col = j0 + nc * 16 + fr;
        sv[nc][r] = (col <= row) ? sA[nc][r] * SC_C : -1e30f;
      }
    #pragma unroll
    for (int r = 0; r < 4; r++) {
      float mx = fmaxf(fmaxf(sv[0][r], sv[1][r]), fmaxf(sv[2][r], sv[3][r]));
      #pragma unroll
      for (int off = 1; off < 16; off <<= 1) mx = fmaxf(mx, __shfl_xor(mx, off, 64));
      float mn = fmaxf(m[r], mx);
      float alpha = __expf(m[r] - mn);
      float ps = 0.f;
      #pragma unroll
      for (int nc = 0; nc < 4; nc++) {
        float p = __expf(sv[nc][r] - mn);
        Ps[band + q * 4 + r][nc * 16 + fr] = f2bu(p);
        ps += p;
      }
      #pragma unroll
      for (int off = 1; off < 16; off <<= 1) ps += __shfl_xor(ps, off, 64);
      l[r] = l[r] * alpha + ps;
      m[r] = mn;
      #pragma unroll
      for (int nc = 0; nc < 4; nc++) oacc[nc][r] *= alpha;
    }
    bf16x8 ap0 = *(const bf16x8*)&Ps[band + fr][q * 8];
    bf16x8 ap1 = *(const bf16x8*)&Ps[band + fr][32 + q * 8];
    #pragma unroll
    for (int nc = 0; nc < 4; nc++) {
      bf16x8 bv0 = *(const bf16x8*)&Vts[rb][nc * 16 + fr][q * 8];
      bf16x8 bv1 = *(const bf16x8*)&Vts[rb][nc * 16 + fr][32 + q * 8];
      oacc[nc] = __builtin_amdgcn_mfma_f32_16x16x32_bf16(ap0, bv0, oacc[nc], 0, 0, 0);
      oacc[nc] = __builtin_amdgcn_mfma_f32_16x16x32_bf16(ap1, bv1, oacc[nc], 0, 0, 0);
    }
    if (jt < it) {
      *(uint4*)&Kts[rb ^ 1][r0][c0] = pk[0];
      *(uint4*)&Kts[rb ^ 1][r0 + 32][c0] = pk[1];
      *(uint4*)&Vts[rb ^ 1][r0][c0] = pv[0];
      *(uint4*)&Vts[rb ^ 1][r0 + 32][c0] = pv[1];
      __syncthreads();
      rb ^= 1;
    }
  }
  // epilogue
  float linv[4];
  #pragma unroll
  for (int r = 0; r < 4; r++) linv[r] = 1.0f / l[r];
  float dpart[4] = {};
  #pragma unroll
  for (int nc = 0; nc < 4; nc++)
    #pragma unroll
    for (int r = 0; r < 4; r++) {
      int row = i0 + band + q * 4 + r;
      size_t gi = (size_t)(b * S_LEN + row) * E_DIM + h * HD + nc * 16 + fr;
      float o = oacc[nc][r] * linv[r];
      float g = o - Xs[gi];
      Gb[gi] = f2bu(g);
      dpart[r] += g * o;
    }
  #pragma unroll
  for (int r = 0; r < 4; r++) {
    #pragma unroll
    for (int off = 1; off < 16; off <<= 1) dpart[r] += __shfl_xor(dpart[r], off, 64);
  }
  if (fr == 0) {
    #pragma unroll
    for (int r = 0; r < 4; r++) {
      size_t sid = (size_t)bh * S_LEN + i0 + band + q * 4 + r;
      mbuf[sid] = m[r];
      lbuf[sid] = linv[r];
      Dv[sid] = dpart[r];
    }
  }
}

// ---- bwd dq: S=QK^T, dP=GV^T, dS->LDS, dq = dS*K^T (Kt tile); pipelined dbuf ----
__global__ __launch_bounds__(256) void bwd_q(const ushort_t* __restrict__ Qg,
                                             const ushort_t* __restrict__ Kg,
                                             const ushort_t* __restrict__ Vg,
                                             const ushort_t* __restrict__ Gg,
                                             const ushort_t* __restrict__ Kt,
                                             const float* __restrict__ mbuf,
                                             const float* __restrict__ lbuf,
                                             const float* __restrict__ Dv,
                                             ushort_t* __restrict__ GQ) {
  int it = 15 - blockIdx.x;
  int bh = blockIdx.y, b = bh >> 4, h = bh & 15;
  int tid = threadIdx.x, lane = tid & 63, wv = tid >> 6;
  int fr = lane & 15, q = lane >> 4;
  int i0 = it * 64, band = wv * 16;
  __shared__ ushort_t Kts[2][64][72];   // [j][d]
  __shared__ ushort_t Vts[2][64][72];   // [j][d]
  __shared__ ushort_t Ktt[2][64][72];   // [d][j]
  __shared__ ushort_t dSs[64][72];

  int r0 = tid >> 3, c0 = (tid & 7) * 8;

  const ushort_t* Qrow = Qg + (size_t)(b * S_LEN + i0 + band + fr) * E_DIM + h * HD;
  const ushort_t* Grow = Gg + (size_t)(b * S_LEN + i0 + band + fr) * E_DIM + h * HD;
  bf16x8 aq0 = ldg8(Qrow + q * 8), aq1 = ldg8(Qrow + 32 + q * 8);
  bf16x8 ag0 = ldg8(Grow + q * 8), ag1 = ldg8(Grow + 32 + q * 8);

  uint4 pk[2], pv[2], pt[2];
  {
    pk[0] = *(const uint4*)(Kg + (size_t)(b * S_LEN + r0) * E_DIM + h * HD + c0);
    pk[1] = *(const uint4*)(Kg + (size_t)(b * S_LEN + r0 + 32) * E_DIM + h * HD + c0);
    pv[0] = *(const uint4*)(Vg + (size_t)(b * S_LEN + r0) * E_DIM + h * HD + c0);
    pv[1] = *(const uint4*)(Vg + (size_t)(b * S_LEN + r0 + 32) * E_DIM + h * HD + c0);
    pt[0] = *(const uint4*)(Kt + (size_t)(bh * HD + r0) * S_LEN + c0);
    pt[1] = *(const uint4*)(Kt + (size_t)(bh * HD + r0 + 32) * S_LEN + c0);
  }
  *(uint4*)&Kts[0][r0][c0] = pk[0];
  *(uint4*)&Kts[0][r0 + 32][c0] = pk[1];
  *(uint4*)&Vts[0][r0][c0] = pv[0];
  *(uint4*)&Vts[0][r0 + 32][c0] = pv[1];
  *(uint4*)&Ktt[0][r0][c0] = pt[0];
  *(uint4*)&Ktt[0][r0 + 32][c0] = pt[1];
  __syncthreads();
  int rb = 0;

  float mrow[4], linv[4], Dr[4];
  #pragma unroll
  for (int r = 0; r < 4; r++) {
    size_t sid = (size_t)bh * S_LEN + i0 + band + q * 4 + r;
    mrow[r] = mbuf[sid]; linv[r] = lbuf[sid]; Dr[r] = Dv[sid];
  }
  f32x4 dqacc[4] = {};

  #pragma unroll 1
  for (int jt = 0; jt <= it; jt++) {
    int j0 = jt * 64;
    if (jt < it) {
      int j0n = j0 + 64;
      pk[0] = *(const uint4*)(Kg + (size_t)(b * S_LEN + j0n + r0) * E_DIM + h * HD + c0);
      pk[1] = *(const uint4*)(Kg + (size_t)(b * S_LEN + j0n + r0 + 32) * E_DIM + h * HD + c0);
      pv[0] = *(const uint4*)(Vg + (size_t)(b * S_LEN + j0n + r0) * E_DIM + h * HD + c0);
      pv[1] = *(const uint4*)(Vg + (size_t)(b * S_LEN + j0n + r0 + 32) * E_DIM + h * HD + c0);
      pt[0] = *(const uint4*)(Kt + (size_t)(bh * HD + r0) * S_LEN + j0n + c0);
      pt[1] = *(const uint4*)(Kt + (size_t)(bh * HD + r0 + 32) * S_LEN + j0n + c0);
    }
    f32x4 sA[4], dpA[4];
    #pragma unroll
    for (int nc = 0; nc < 4; nc++) {
      bf16x8 bk0 = *(const bf16x8*)&Kts[rb][nc * 16 + fr][q * 8];
      bf16x8 bk1 = *(const bf16x8*)&Kts[rb][nc * 16 + fr][32 + q * 8];
      bf16x8 bv0 = *(const bf16x8*)&Vts[rb][nc * 16 + fr][q * 8];
      bf16x8 bv1 = *(const bf16x8*)&Vts[rb][nc * 16 + fr][32 + q * 8];
      f32x4 z = {};
      z = __builtin_amdgcn_mfma_f32_16x16x32_bf16(aq0, bk0, z, 0, 0, 0);
      sA[nc] = __builtin_amdgcn_mfma_f32_16x16x32_bf16(aq1, bk1, z, 0, 0, 0);
      f32x4 z2 = {};
      z2 = __builtin_amdgcn_mfma_f32_16x16x32_bf16(ag0, bv0, z2, 0, 0, 0);
      dpA[nc] = __builtin_amdgcn_mfma_f32_16x16x32_bf16(ag1, bv1, z2, 0, 0, 0);
    }
    #pragma unroll
    for (int nc = 0; nc < 4; nc++)
      #pragma unroll
      for (int r = 0; r < 4; r++) {
        int row = i0 + band + q * 4 + r;
        int col = j0 + nc * 16 + fr;
        float ds = 0.f;
        if (col <= row) {
          float P = __expf(sA[nc][r] * SC_C - mrow[r]) * linv[r];
          ds = P * (dpA[nc][r] - Dr[r]) * SC_C;
        }
        dSs[band + q * 4 + r][nc * 16 + fr] = f2bu(ds);  // wave-private
      }
    bf16x8 ad0 = *(const bf16x8*)&dSs[band + fr][q * 8];
    bf16x8 ad1 = *(const bf16x8*)&dSs[band + fr][32 + q * 8];
    #pragma unroll
    for (int nc = 0; nc < 4; nc++) {
      bf16x8 bt0 = *(const bf16x8*)&Ktt[rb][nc * 16 + fr][q * 8];
      bf16x8 bt1 = *(const bf16x8*)&Ktt[rb][nc * 16 + fr][32 + q * 8];
      dqacc[nc] = __builtin_amdgcn_mfma_f32_16x16x32_bf16(ad0, bt0, dqacc[nc], 0, 0, 0);
      dqacc[nc] = __builtin_amdgcn_mfma_f32_16x16x32_bf16(ad1, bt1, dqacc[nc], 0, 0, 0);
    }
    if (jt < it) {
      *(uint4*)&Kts[rb ^ 1][r0][c0] = pk[0];
      *(uint4*)&Kts[rb ^ 1][r0 + 32][c0] = pk[1];
      *(uint4*)&Vts[rb ^ 1][r0][c0] = pv[0];
      *(uint4*)&Vts[rb ^ 1][r0 + 32][c0] = pv[1];
      *(uint4*)&Ktt[rb ^ 1][r0][c0] = pt[0];
      *(uint4*)&Ktt[rb ^ 1][r0 + 32][c0] = pt[1];
      __syncthreads();
      rb ^= 1;
    }
  }
  #pragma unroll
  for (int nc = 0; nc < 4; nc++)
    #pragma unroll
    for (int r = 0; r < 4; r++) {
      int row = i0 + band + q * 4 + r;
      size_t gi = (size_t)(b * S_LEN + row) * E_DIM + h * HD + nc * 16 + fr;
      GQ[gi] = f2bu(dqacc[nc][r]);
    }
}

// ---- bwd dk/dv: single-buffer + register prefetch (4 staged tiles) ----
__global__ __launch_bounds__(256) void bwd_kv(const ushort_t* __restrict__ Qg,
                                              const ushort_t* __restrict__ Kg,
                                              const ushort_t* __restrict__ Vg,
                                              const ushort_t* __restrict__ Gg,
                                              const ushort_t* __restrict__ Qt,
                                              const ushort_t* __restrict__ Gt,
                                              const float* __restrict__ mbuf,
                                              const float* __restrict__ lbuf,
                                              const float* __restrict__ Dv,
                                              ushort_t* __restrict__ GK,
                                              ushort_t* __restrict__ GV) {
  int jt = blockIdx.x;  // jt=0 heaviest, dispatched first
  int bh = blockIdx.y, b = bh >> 4, h = bh & 15;
  int tid = threadIdx.x, lane = tid & 63, wv = tid >> 6;
  int fr = lane & 15, q = lane >> 4;
  int j0 = jt * 64, band = wv * 16;
  __shared__ ushort_t Qs_[64][72];  // [i][d]
  __shared__ ushort_t Gs_[64][72];  // [i][d]
  __shared__ ushort_t Qtt[64][72];  // [d][i]
  __shared__ ushort_t Gtt[64][72];  // [d][i]
  __shared__ ushort_t PT[64][72];   // [j][i]
  __shared__ ushort_t dST[64][72];  // [j][i]

  int r0 = tid >> 3, c0 = (tid & 7) * 8;

  const ushort_t* Krow = Kg + (size_t)(b * S_LEN + j0 + band + fr) * E_DIM + h * HD;
  const ushort_t* Vrow = Vg + (size_t)(b * S_LEN + j0 + band + fr) * E_DIM + h * HD;
  bf16x8 ak0 = ldg8(Krow + q * 8), ak1 = ldg8(Krow + 32 + q * 8);
  bf16x8 av0 = ldg8(Vrow + q * 8), av1 = ldg8(Vrow + 32 + q * 8);

  f32x4 dkacc[4] = {}, dvacc[4] = {};

  uint4 pq[2], pg[2], pqt[2], pgt[2];
  float mcN[4], lcN[4], DcN[4];
  {
    int i0 = j0;
    pq[0] = *(const uint4*)(Qg + (size_t)(b * S_LEN + i0 + r0) * E_DIM + h * HD + c0);
    pq[1] = *(const uint4*)(Qg + (size_t)(b * S_LEN + i0 + r0 + 32) * E_DIM + h * HD + c0);
    pg[0] = *(const uint4*)(Gg + (size_t)(b * S_LEN + i0 + r0) * E_DIM + h * HD + c0);
    pg[1] = *(const uint4*)(Gg + (size_t)(b * S_LEN + i0 + r0 + 32) * E_DIM + h * HD + c0);
    pqt[0] = *(const uint4*)(Qt + (size_t)(bh * HD + r0) * S_LEN + i0 + c0);
    pqt[1] = *(const uint4*)(Qt + (size_t)(bh * HD + r0 + 32) * S_LEN + i0 + c0);
    pgt[0] = *(const uint4*)(Gt + (size_t)(bh * HD + r0) * S_LEN + i0 + c0);
    pgt[1] = *(const uint4*)(Gt + (size_t)(bh * HD + r0 + 32) * S_LEN + i0 + c0);
    #pragma unroll
    for (int nc = 0; nc < 4; nc++) {
      size_t sid = (size_t)bh * S_LEN + i0 + nc * 16 + fr;
      mcN[nc] = mbuf[sid]; lcN[nc] = lbuf[sid]; DcN[nc] = Dv[sid];
    }
  }

  #pragma unroll 1
  for (int i_t = jt; i_t < 16; i_t++) {
    int i0 = i_t * 64;
    __syncthreads();  // protect staged LDS from prior iteration's reads
    *(uint4*)&Qs_[r0][c0] = pq[0];
    *(uint4*)&Qs_[r0 + 32][c0] = pq[1];
    *(uint4*)&Gs_[r0][c0] = pg[0];
    *(uint4*)&Gs_[r0 + 32][c0] = pg[1];
    *(uint4*)&Qtt[r0][c0] = pqt[0];
    *(uint4*)&Qtt[r0 + 32][c0] = pqt[1];
    *(uint4*)&Gtt[r0][c0] = pgt[0];
    *(uint4*)&Gtt[r0 + 32][c0] = pgt[1];
    __syncthreads();
    float mc[4], lc[4], Dc[4];
    #pragma unroll
    for (int nc = 0; nc < 4; nc++) { mc[nc] = mcN[nc]; lc[nc] = lcN[nc]; Dc[nc] = DcN[nc]; }
    if (i_t < 15) {
      int i0n = i0 + 64;
      pq[0] = *(const uint4*)(Qg + (size_t)(b * S_LEN + i0n + r0) * E_DIM + h * HD + c0);
      pq[1] = *(const uint4*)(Qg + (size_t)(b * S_LEN + i0n + r0 + 32) * E_DIM + h * HD + c0);
      pg[0] = *(const uint4*)(Gg + (size_t)(b * S_LEN + i0n + r0) * E_DIM + h * HD + c0);
      pg[1] = *(const uint4*)(Gg + (size_t)(b * S_LEN + i0n + r0 + 32) * E_DIM + h * HD + c0);
      pqt[0] = *(const uint4*)(Qt + (size_t)(bh * HD + r0) * S_LEN + i0n + c0);
      pqt[1] = *(const uint4*)(Qt + (size_t)(bh * HD + r0 + 32) * S_LEN + i0n + c0);
      pgt[0] = *(const uint4*)(Gt + (size_t)(bh * HD + r0) * S_LEN + i0n + c0);
      pgt[1] = *(const uint4*)(Gt + (size_t)(bh * HD + r0 + 32) * S_LEN + i0n + c0);
      #pragma unroll
      for (int nc = 0; nc < 4; nc++) {
        size_t sid = (size_t)bh * S_LEN + i0n + nc * 16 + fr;
        mcN[nc] = mbuf[sid]; lcN[nc] = lbuf[sid]; DcN[nc] = Dv[sid];
      }
    }
    f32x4 stA[4], dptA[4];
    #pragma unroll
    for (int nc = 0; nc < 4; nc++) {
      bf16x8 bq0 = *(const bf16x8*)&Qs_[nc * 16 + fr][q * 8];
      bf16x8 bq1 = *(const bf16x8*)&Qs_[nc * 16 + fr][32 + q * 8];
      bf16x8 bg0 = *(const bf16x8*)&Gs_[nc * 16 + fr][q * 8];
      bf16x8 bg1 = *(const bf16x8*)&Gs_[nc * 16 + fr][32 + q * 8];
      f32x4 z = {};
      z = __builtin_amdgcn_mfma_f32_16x16x32_bf16(ak0, bq0, z, 0, 0, 0);
      stA[nc] = __builtin_amdgcn_mfma_f32_16x16x32_bf16(ak1, bq1, z, 0, 0, 0);
      f32x4 z2 = {};
      z2 = __builtin_amdgcn_mfma_f32_16x16x32_bf16(av0, bg0, z2, 0, 0, 0);
      dptA[nc] = __builtin_amdgcn_mfma_f32_16x16x32_bf16(av1, bg1, z2, 0, 0, 0);
    }
    #pragma unroll
    for (int nc = 0; nc < 4; nc++)
      #pragma unroll
      for (int r = 0; r < 4; r++) {
        int jrow = j0 + band + q * 4 + r;
        int icol = i0 + nc * 16 + fr;
        float P = 0.f, ds = 0.f;
        if (icol >= jrow) {
          P = __expf(stA[nc][r] * SC_C - mc[nc]) * lc[nc];
          ds = P * (dptA[nc][r] - Dc[nc]) * SC_C;
        }
        PT[band + q * 4 + r][nc * 16 + fr] = f2bu(P);   // wave-private
        dST[band + q * 4 + r][nc * 16 + fr] = f2bu(ds);
      }
    bf16x8 ap0 = *(const bf16x8*)&PT[band + fr][q * 8];
    bf16x8 ap1 = *(const bf16x8*)&PT[band + fr][32 + q * 8];
    bf16x8 ad0 = *(const bf16x8*)&dST[band + fr][q * 8];
    bf16x8 ad1 = *(const bf16x8*)&dST[band + fr][32 + q * 8];
    #pragma unroll
    for (int nc = 0; nc < 4; nc++) {
      bf16x8 bg0 = *(const bf16x8*)&Gtt[nc * 16 + fr][q * 8];
      bf16x8 bg1 = *(const bf16x8*)&Gtt[nc * 16 + fr][32 + q * 8];
      bf16x8 bq0 = *(const bf16x8*)&Qtt[nc * 16 + fr][q * 8];
      bf16x8 bq1 = *(const bf16x8*)&Qtt[nc * 16 + fr][32 + q * 8];
      dvacc[nc] = __builtin_amdgcn_mfma_f32_16x16x32_bf16(ap0, bg0, dvacc[nc], 0, 0, 0);
      dvacc[nc] = __builtin_amdgcn_mfma_f32_16x16x32_bf16(ap1, bg1, dvacc[nc], 0, 0, 0);
      dkacc[nc] = __builtin_amdgcn_mfma_f32_16x16x32_bf16(ad0, bq0, dkacc[nc], 0, 0, 0);
      dkacc[nc] = __builtin_amdgcn_mfma_f32_16x16x32_bf16(ad1, bq1, dkacc[nc], 0, 0, 0);
    }
  }
  #pragma unroll
  for (int nc = 0; nc < 4; nc++)
    #pragma unroll
    for (int r = 0; r < 4; r++) {
      int jrow = j0 + band + q * 4 + r;
      size_t gi = (size_t)(b * S_LEN + jrow) * E_DIM + h * HD + nc * 16 + fr;
      GK[gi] = f2bu(dkacc[nc][r]);
      GV[gi] = f2bu(dvacc[nc][r]);
    }
}

// ---------------- launch ----------------
extern "C" void kernel_launch(void* const* d_in, const int* in_sizes, int n_in,
                              void* d_out, int out_size, void* d_ws, size_t ws_size,
                              hipStream_t stream) {
  const float* T1 = (const float*)d_in[0];
  const float* Wq = (const float*)d_in[1];
  const float* Wk = (const float*)d_in[2];
  const float* Wv = (const float*)d_in[3];
  const float* Wo = (const float*)d_in[4];

  const size_t M2 = 2097152;   // 2048*1024
  const size_t M1 = 1048576;
  float* w = (float*)d_ws;
  float* Xs = w;                       // 8 MB fp32 target
  float* mS = Xs + M2;                 // 64K f32
  float* lS = mS + 65536;
  float* DvS = lS + 65536;
  ushort_t* u = (ushort_t*)(DvS + 65536);
  ushort_t* W0 = u;          ushort_t* W1 = W0 + M1;  ushort_t* W2 = W1 + M1;
  ushort_t* W3 = W2 + M1;    ushort_t* W4 = W3 + M1;  ushort_t* W5 = W4 + M1;
  ushort_t* Qb = W5 + M1;    ushort_t* Kb = Qb + M2;  ushort_t* Vb = Kb + M2;
  ushort_t* Qt = Vb + M2;    ushort_t* Kt = Qt + M2;  ushort_t* Vt = Kt + M2;
  ushort_t* Gt = Vt + M2;
  ushort_t* Gb = Gt + M2;
  ushort_t* GQb = Gb + M2;   ushort_t* GKb = GQb + M2; ushort_t* GVb = GKb + M2;
  ushort_t* X2b = GVb + M2;
  ushort_t* Rb = GQb;        // stage-1 aliases
  ushort_t* Xsb = GKb;
  float* X2 = (float*)d_out;

  hipMemsetAsync(Xs, 0, M2 * sizeof(float), stream);
  hipMemsetAsync(Xsb, 0, M2 * sizeof(ushort_t), stream);
  hipMemsetAsync(X2, 0, M2 * sizeof(float), stream);
  hipMemsetAsync(X2b, 0, M2 * sizeof(ushort_t), stream);

  dim3 pgrid(16, 16);
  dim3 ggrid(8, 32);
  dim3 ggrid3(8, 32, 3);
  dim3 agrid(16, BH_CNT);
  dim3 tgrid3(16, BH_CNT, 3);
  dim3 tgrid1(16, BH_CNT, 1);

  // ---- stage 1 ----
  prep_w<<<pgrid, 256, 0, stream>>>(Wo, W0, W1);
  for (int t = 0; t < 3; t++) {
    gemm_mf<1, 1><<<ggrid, 256, 0, stream>>>(Xsb, nullptr, nullptr, W0, nullptr, nullptr,
                                             nullptr, T1, Rb, nullptr, nullptr, 0.f);
    gemm_mf<2, 1><<<ggrid, 256, 0, stream>>>(Rb, nullptr, nullptr, W1, nullptr, nullptr,
                                             Xs, nullptr, Xsb, nullptr, nullptr, LR_C);
  }
  prep_w<<<pgrid, 256, 0, stream>>>(Wq, W0, W3);
  prep_w<<<pgrid, 256, 0, stream>>>(Wk, W1, W4);
  prep_w<<<pgrid, 256, 0, stream>>>(Wv, W2, W5);

  // ---- stage 2 ----
  for (int t = 0; t < 3; t++) {
    gemm_mf<0, 1><<<ggrid3, 256, 0, stream>>>(X2b, nullptr, nullptr, W0, W1, W2,
                                              nullptr, nullptr, Qb, Kb, Vb, 0.f);
    tr_head<<<tgrid3, 256, 0, stream>>>(Qb, Kb, Vb, Qt, Kt, Vt);
    fwd_fused<<<agrid, 256, 0, stream>>>(Qb, Kb, Vt, Xs, mS, lS, Gb, DvS);
    tr_head<<<tgrid1, 256, 0, stream>>>(Gb, nullptr, nullptr, Gt, nullptr, nullptr);
    bwd_q<<<agrid, 256, 0, stream>>>(Qb, Kb, Vb, Gb, Kt, mS, lS, DvS, GQb);
    bwd_kv<<<agrid, 256, 0, stream>>>(Qb, Kb, Vb, Gb, Qt, Gt, mS, lS, DvS, GKb, GVb);
    gemm_mf<2, 3><<<ggrid, 256, 0, stream>>>(GQb, GKb, GVb, W3, W4, W5,
                                             X2, nullptr, X2b, nullptr, nullptr, -LR_C);
  }
}

// Round 8
// 881.244 us; speedup vs baseline: 1.2444x; 1.2444x over previous
//
#include <hip/hip_runtime.h>
#include <hip/hip_bf16.h>

// Problem constants (B=2, S=1024, E=1024, H=16, D=64)
#define S_LEN 1024
#define E_DIM 1024
#define NH 16
#define HD 64
#define M_ROWS 2048   // B*S
#define BH_CNT 32     // B*NH

static constexpr float LR_C = 0.01f;
static constexpr float SC_C = 0.125f;  // 1/sqrt(64)

typedef unsigned short ushort_t;
typedef __attribute__((ext_vector_type(8))) __bf16 bf16x8;
typedef __attribute__((ext_vector_type(4))) float f32x4;

static __device__ inline ushort_t f2bu(float f) {
  __hip_bfloat16 h = __float2bfloat16(f);
  return *(ushort_t*)&h;
}
static __device__ inline bf16x8 ldg8(const ushort_t* p) { return *(const bf16x8*)p; }

// ---------------- weight prep: bf16 cast + bf16 transpose, 64x64 tiles ----------------
__global__ __launch_bounds__(256) void prep_w(const float* __restrict__ W,
                                              ushort_t* __restrict__ Wb,
                                              ushort_t* __restrict__ WTb) {
  __shared__ float ts[64][65];
  int bx = blockIdx.x * 64, by = blockIdx.y * 64;
  int t = threadIdx.x;
  int rr = t >> 6, cc = t & 63;
  #pragma unroll
  for (int p = 0; p < 16; p++) {
    int r = p * 4 + rr;
    float v = W[(size_t)(by + r) * E_DIM + bx + cc];
    ts[r][cc] = v;
    Wb[(size_t)(by + r) * E_DIM + bx + cc] = f2bu(v);
  }
  __syncthreads();
  #pragma unroll
  for (int p = 0; p < 16; p++) {
    int r = p * 4 + rr;
    WTb[(size_t)(bx + r) * E_DIM + by + cc] = f2bu(ts[cc][r]);
  }
}

// ---------------- bf16 MFMA GEMM: C[2048,1024] = A[M,K=1024] * B[N,K]^T ----------------
// MODE 0: Cb_z = bf16(acc), and Ct_z = per-head-transposed bf16 [bh][d][token]  [QKV proj]
// MODE 1: Cb0 = bf16(T - acc)                                                  [stage-1 residual]
// MODE 2: Cf += alpha*acc (fp32) and Cb0 = bf16(Cf), NSEG K-segments           [PC update]
template <int MODE, int NSEG>
__global__ __launch_bounds__(256) void gemm_mf(
    const ushort_t* __restrict__ A0, const ushort_t* __restrict__ A1, const ushort_t* __restrict__ A2,
    const ushort_t* __restrict__ B0, const ushort_t* __restrict__ B1, const ushort_t* __restrict__ B2,
    float* __restrict__ Cf, const float* __restrict__ T,
    ushort_t* __restrict__ Cb0, ushort_t* __restrict__ Cb1, ushort_t* __restrict__ Cb2,
    ushort_t* __restrict__ Ct0, ushort_t* __restrict__ Ct1, ushort_t* __restrict__ Ct2,
    float alpha) {
  const int K = 1024;
  __shared__ __bf16 As[64][40];
  __shared__ __bf16 Bs[128][40];
  int tid = threadIdx.x;
  int m0 = blockIdx.y * 64, n0 = blockIdx.x * 128;

  const ushort_t* Bsel = B0;
  ushort_t* Cbz = Cb0;
  ushort_t* Ctz = Ct0;
  if (MODE == 0) {
    int z = blockIdx.z;
    Bsel = (z == 0) ? B0 : (z == 1) ? B1 : B2;
    Cbz = (z == 0) ? Cb0 : (z == 1) ? Cb1 : Cb2;
    Ctz = (z == 0) ? Ct0 : (z == 1) ? Ct1 : Ct2;
  }

  int lane = tid & 63, wave = tid >> 6;
  int wrow = wave >> 1, wcol = wave & 1;
  int fr = lane & 15, q = lane >> 4;

  f32x4 acc[2][4] = {};

  int ar = tid >> 2, ac = (tid & 3) * 8;
  #pragma unroll 1
  for (int seg = 0; seg < NSEG; seg++) {
    const ushort_t* Aseg = (seg == 0) ? A0 : (seg == 1) ? A1 : A2;
    const ushort_t* Bseg = (MODE == 0) ? Bsel : ((seg == 0) ? B0 : (seg == 1) ? B1 : B2);
    const ushort_t* Ag = Aseg + (size_t)(m0 + ar) * K + ac;
    const ushort_t* Bg0 = Bseg + (size_t)(n0 + ar) * K + ac;
    const ushort_t* Bg1 = Bseg + (size_t)(n0 + 64 + ar) * K + ac;
    for (int k0 = 0; k0 < K; k0 += 32) {
      uint4 av = *(const uint4*)(Ag + k0);
      uint4 bv0 = *(const uint4*)(Bg0 + k0);
      uint4 bv1 = *(const uint4*)(Bg1 + k0);
      __syncthreads();
      *(uint4*)&As[ar][ac] = av;
      *(uint4*)&Bs[ar][ac] = bv0;
      *(uint4*)&Bs[64 + ar][ac] = bv1;
      __syncthreads();
      bf16x8 a0 = *(const bf16x8*)&As[wrow * 32 + fr][q * 8];
      bf16x8 a1 = *(const bf16x8*)&As[wrow * 32 + 16 + fr][q * 8];
      bf16x8 b0 = *(const bf16x8*)&Bs[wcol * 64 + fr][q * 8];
      bf16x8 b1 = *(const bf16x8*)&Bs[wcol * 64 + 16 + fr][q * 8];
      bf16x8 b2 = *(const bf16x8*)&Bs[wcol * 64 + 32 + fr][q * 8];
      bf16x8 b3 = *(const bf16x8*)&Bs[wcol * 64 + 48 + fr][q * 8];
      acc[0][0] = __builtin_amdgcn_mfma_f32_16x16x32_bf16(a0, b0, acc[0][0], 0, 0, 0);
      acc[0][1] = __builtin_amdgcn_mfma_f32_16x16x32_bf16(a0, b1, acc[0][1], 0, 0, 0);
      acc[0][2] = __builtin_amdgcn_mfma_f32_16x16x32_bf16(a0, b2, acc[0][2], 0, 0, 0);
      acc[0][3] = __builtin_amdgcn_mfma_f32_16x16x32_bf16(a0, b3, acc[0][3], 0, 0, 0);
      acc[1][0] = __builtin_amdgcn_mfma_f32_16x16x32_bf16(a1, b0, acc[1][0], 0, 0, 0);
      acc[1][1] = __builtin_amdgcn_mfma_f32_16x16x32_bf16(a1, b1, acc[1][1], 0, 0, 0);
      acc[1][2] = __builtin_amdgcn_mfma_f32_16x16x32_bf16(a1, b2, acc[1][2], 0, 0, 0);
      acc[1][3] = __builtin_amdgcn_mfma_f32_16x16x32_bf16(a1, b3, acc[1][3], 0, 0, 0);
    }
  }

  // C/D layout: col = lane&15, row = (lane>>4)*4 + reg
  #pragma unroll
  for (int mi = 0; mi < 2; mi++)
    #pragma unroll
    for (int ni = 0; ni < 4; ni++) {
      int col = n0 + wcol * 64 + ni * 16 + fr;
      int row0 = m0 + wrow * 32 + mi * 16 + q * 4;
      ushort_t pk[4];
      #pragma unroll
      for (int r = 0; r < 4; r++) {
        size_t idx = (size_t)(row0 + r) * E_DIM + col;
        float v = acc[mi][ni][r];
        if (MODE == 0) {
          ushort_t bu = f2bu(v);
          pk[r] = bu;
          Cbz[idx] = bu;
        } else if (MODE == 1) {
          Cb0[idx] = f2bu(T[idx] - v);
        } else {
          float nv = Cf[idx] + alpha * v;
          Cf[idx] = nv;
          Cb0[idx] = f2bu(nv);
        }
      }
      if (MODE == 0) {
        // transposed write: Xt[(b*16+h)*64 + d][token], 4 consecutive tokens -> one 8B store
        int hh = col >> 6, dd = col & 63;
        int bb = row0 >> 10, ss = row0 & 1023;
        *(uint2*)(Ctz + ((size_t)((bb * NH + hh) * HD + dd)) * S_LEN + ss) = *(uint2*)pk;
      }
    }
}

// ====================== MFMA attention, LDS-staged (R6-proven) ======================
// MFMA 16x16x32: A[m=lane&15][k=q*8+u], B[n=lane&15][k=q*8+u], C: col=lane&15, row=q*4+reg.
// Block: 64-row tile, 4 waves = 4 bands of 16. Staged tiles padded to 72 (2-way banks).

// ---- fused fwd: single-pass flash, online softmax; emits m, 1/l, g=O-Xs (bf16 + transposed), Dv ----
__global__ __launch_bounds__(256) void fwd_fused(const ushort_t* __restrict__ Qg,
                                                 const ushort_t* __restrict__ Kg,
                                                 const ushort_t* __restrict__ Vt,
                                                 const float* __restrict__ Xs,
                                                 float* __restrict__ mbuf,
                                                 float* __restrict__ lbuf,
                                                 ushort_t* __restrict__ Gb,
                                                 ushort_t* __restrict__ Gt,
                                                 float* __restrict__ Dv) {
  int it = 15 - blockIdx.x;
  int bh = blockIdx.y, b = bh >> 4, h = bh & 15;
  int tid = threadIdx.x, lane = tid & 63, wv = tid >> 6;
  int fr = lane & 15, q = lane >> 4;
  int i0 = it * 64, band = wv * 16;
  __shared__ ushort_t Kts[64][72];  // [j][d]
  __shared__ ushort_t Vts[64][72];  // [d][j]
  __shared__ ushort_t Ps[64][72];   // [i][j] wave-private bands

  const ushort_t* Qrow = Qg + (size_t)(b * S_LEN + i0 + band + fr) * E_DIM + h * HD;
  bf16x8 aq0 = ldg8(Qrow + q * 8);
  bf16x8 aq1 = ldg8(Qrow + 32 + q * 8);

  float m[4], l[4];
  #pragma unroll
  for (int r = 0; r < 4; r++) { m[r] = -1e30f; l[r] = 0.f; }
  f32x4 oacc[4] = {};

  #pragma unroll 1
  for (int jt = 0; jt <= it; jt++) {
    int j0 = jt * 64;
    __syncthreads();
    #pragma unroll
    for (int t = 0; t < 2; t++) {
      int u = tid + 256 * t;
      int r = u >> 3, c8 = (u & 7) * 8;
      *(uint4*)&Kts[r][c8] = *(const uint4*)(Kg + (size_t)(b * S_LEN + j0 + r) * E_DIM + h * HD + c8);
      *(uint4*)&Vts[r][c8] = *(const uint4*)(Vt + (size_t)(bh * HD + r) * S_LEN + j0 + c8);
    }
    __syncthreads();
    f32x4 sA[4];
    #pragma unroll
    for (int nc = 0; nc < 4; nc++) {
      bf16x8 bk0 = *(const bf16x8*)&Kts[nc * 16 + fr][q * 8];
      bf16x8 bk1 = *(const bf16x8*)&Kts[nc * 16 + fr][32 + q * 8];
      f32x4 z = {};
      z = __builtin_amdgcn_mfma_f32_16x16x32_bf16(aq0, bk0, z, 0, 0, 0);
      sA[nc] = __builtin_amdgcn_mfma_f32_16x16x32_bf16(aq1, bk1, z, 0, 0, 0);
    }
    float sv[4][4];
    #pragma unroll
    for (int nc = 0; nc < 4; nc++)
      #pragma unroll
      for (int r = 0; r < 4; r++) {
        int row = i0 + band + q * 4 + r;
        int col = j0 + nc * 16 + fr;
        sv[nc][r] = (col <= row) ? sA[nc][r] * SC_C : -1e30f;
      }
    #pragma unroll
    for (int r = 0; r < 4; r++) {
      float mx = fmaxf(fmaxf(sv[0][r], sv[1][r]), fmaxf(sv[2][r], sv[3][r]));
      #pragma unroll
      for (int off = 1; off < 16; off <<= 1) mx = fmaxf(mx, __shfl_xor(mx, off, 64));
      float mn = fmaxf(m[r], mx);
      float alpha = __expf(m[r] - mn);
      float ps = 0.f;
      #pragma unroll
      for (int nc = 0; nc < 4; nc++) {
        float p = __expf(sv[nc][r] - mn);
        Ps[band + q * 4 + r][nc * 16 + fr] = f2bu(p);
        ps += p;
      }
      #pragma unroll
      for (int off = 1; off < 16; off <<= 1) ps += __shfl_xor(ps, off, 64);
      l[r] = l[r] * alpha + ps;
      m[r] = mn;
      #pragma unroll
      for (int nc = 0; nc < 4; nc++) oacc[nc][r] *= alpha;
    }
    bf16x8 ap0 = *(const bf16x8*)&Ps[band + fr][q * 8];
    bf16x8 ap1 = *(const bf16x8*)&Ps[band + fr][32 + q * 8];
    #pragma unroll
    for (int nc = 0; nc < 4; nc++) {
      bf16x8 bv0 = *(const bf16x8*)&Vts[nc * 16 + fr][q * 8];
      bf16x8 bv1 = *(const bf16x8*)&Vts[nc * 16 + fr][32 + q * 8];
      oacc[nc] = __builtin_amdgcn_mfma_f32_16x16x32_bf16(ap0, bv0, oacc[nc], 0, 0, 0);
      oacc[nc] = __builtin_amdgcn_mfma_f32_16x16x32_bf16(ap1, bv1, oacc[nc], 0, 0, 0);
    }
  }
  // epilogue: g = O - Xs (bf16 normal + transposed), Dv partials
  float linv[4];
  #pragma unroll
  for (int r = 0; r < 4; r++) linv[r] = 1.0f / l[r];
  float dpart[4] = {};
  #pragma unroll
  for (int nc = 0; nc < 4; nc++) {
    ushort_t pg[4];
    #pragma unroll
    for (int r = 0; r < 4; r++) {
      int row = i0 + band + q * 4 + r;
      size_t gi = (size_t)(b * S_LEN + row) * E_DIM + h * HD + nc * 16 + fr;
      float o = oacc[nc][r] * linv[r];
      float g = o - Xs[gi];
      ushort_t bu = f2bu(g);
      Gb[gi] = bu;
      pg[r] = bu;
      dpart[r] += g * o;
    }
    int d = nc * 16 + fr;
    int s0 = i0 + band + q * 4;
    *(uint2*)(Gt + ((size_t)bh * HD + d) * S_LEN + s0) = *(uint2*)pg;
  }
  #pragma unroll
  for (int r = 0; r < 4; r++) {
    #pragma unroll
    for (int off = 1; off < 16; off <<= 1) dpart[r] += __shfl_xor(dpart[r], off, 64);
  }
  if (fr == 0) {
    #pragma unroll
    for (int r = 0; r < 4; r++) {
      size_t sid = (size_t)bh * S_LEN + i0 + band + q * 4 + r;
      mbuf[sid] = m[r];
      lbuf[sid] = linv[r];
      Dv[sid] = dpart[r];
    }
  }
}

// ---- bwd dq: S=QK^T, dP=GV^T, dS->LDS, dq = dS*K^T (Kt tile) ----
__global__ __launch_bounds__(256) void bwd_q(const ushort_t* __restrict__ Qg,
                                             const ushort_t* __restrict__ Kg,
                                             const ushort_t* __restrict__ Vg,
                                             const ushort_t* __restrict__ Gg,
                                             const ushort_t* __restrict__ Kt,
                                             const float* __restrict__ mbuf,
                                             const float* __restrict__ lbuf,
                                             const float* __restrict__ Dv,
                                             ushort_t* __restrict__ GQ) {
  int it = 15 - blockIdx.x;
  int bh = blockIdx.y, b = bh >> 4, h = bh & 15;
  int tid = threadIdx.x, lane = tid & 63, wv = tid >> 6;
  int fr = lane & 15, q = lane >> 4;
  int i0 = it * 64, band = wv * 16;
  __shared__ ushort_t Kts[64][72];   // [j][d]
  __shared__ ushort_t Vts[64][72];   // [j][d]
  __shared__ ushort_t Ktt[64][72];   // [d][j]
  __shared__ ushort_t dSs[64][72];

  const ushort_t* Qrow = Qg + (size_t)(b * S_LEN + i0 + band + fr) * E_DIM + h * HD;
  const ushort_t* Grow = Gg + (size_t)(b * S_LEN + i0 + band + fr) * E_DIM + h * HD;
  bf16x8 aq0 = ldg8(Qrow + q * 8), aq1 = ldg8(Qrow + 32 + q * 8);
  bf16x8 ag0 = ldg8(Grow + q * 8), ag1 = ldg8(Grow + 32 + q * 8);

  float mrow[4], linv[4], Dr[4];
  #pragma unroll
  for (int r = 0; r < 4; r++) {
    size_t sid = (size_t)bh * S_LEN + i0 + band + q * 4 + r;
    mrow[r] = mbuf[sid]; linv[r] = lbuf[sid]; Dr[r] = Dv[sid];
  }
  f32x4 dqacc[4] = {};

  #pragma unroll 1
  for (int jt = 0; jt <= it; jt++) {
    int j0 = jt * 64;
    __syncthreads();
    #pragma unroll
    for (int t = 0; t < 2; t++) {
      int u = tid + 256 * t;
      int r = u >> 3, c8 = (u & 7) * 8;
      *(uint4*)&Kts[r][c8] = *(const uint4*)(Kg + (size_t)(b * S_LEN + j0 + r) * E_DIM + h * HD + c8);
      *(uint4*)&Vts[r][c8] = *(const uint4*)(Vg + (size_t)(b * S_LEN + j0 + r) * E_DIM + h * HD + c8);
      *(uint4*)&Ktt[r][c8] = *(const uint4*)(Kt + (size_t)(bh * HD + r) * S_LEN + j0 + c8);
    }
    __syncthreads();
    f32x4 sA[4], dpA[4];
    #pragma unroll
    for (int nc = 0; nc < 4; nc++) {
      bf16x8 bk0 = *(const bf16x8*)&Kts[nc * 16 + fr][q * 8];
      bf16x8 bk1 = *(const bf16x8*)&Kts[nc * 16 + fr][32 + q * 8];
      bf16x8 bv0 = *(const bf16x8*)&Vts[nc * 16 + fr][q * 8];
      bf16x8 bv1 = *(const bf16x8*)&Vts[nc * 16 + fr][32 + q * 8];
      f32x4 z = {};
      z = __builtin_amdgcn_mfma_f32_16x16x32_bf16(aq0, bk0, z, 0, 0, 0);
      sA[nc] = __builtin_amdgcn_mfma_f32_16x16x32_bf16(aq1, bk1, z, 0, 0, 0);
      f32x4 z2 = {};
      z2 = __builtin_amdgcn_mfma_f32_16x16x32_bf16(ag0, bv0, z2, 0, 0, 0);
      dpA[nc] = __builtin_amdgcn_mfma_f32_16x16x32_bf16(ag1, bv1, z2, 0, 0, 0);
    }
    #pragma unroll
    for (int nc = 0; nc < 4; nc++)
      #pragma unroll
      for (int r = 0; r < 4; r++) {
        int row = i0 + band + q * 4 + r;
        int col = j0 + nc * 16 + fr;
        float ds = 0.f;
        if (col <= row) {
          float P = __expf(sA[nc][r] * SC_C - mrow[r]) * linv[r];
          ds = P * (dpA[nc][r] - Dr[r]) * SC_C;
        }
        dSs[band + q * 4 + r][nc * 16 + fr] = f2bu(ds);  // wave-private
      }
    bf16x8 ad0 = *(const bf16x8*)&dSs[band + fr][q * 8];
    bf16x8 ad1 = *(const bf16x8*)&dSs[band + fr][32 + q * 8];
    #pragma unroll
    for (int nc = 0; nc < 4; nc++) {
      bf16x8 bt0 = *(const bf16x8*)&Ktt[nc * 16 + fr][q * 8];
      bf16x8 bt1 = *(const bf16x8*)&Ktt[nc * 16 + fr][32 + q * 8];
      dqacc[nc] = __builtin_amdgcn_mfma_f32_16x16x32_bf16(ad0, bt0, dqacc[nc], 0, 0, 0);
      dqacc[nc] = __builtin_amdgcn_mfma_f32_16x16x32_bf16(ad1, bt1, dqacc[nc], 0, 0, 0);
    }
  }
  #pragma unroll
  for (int nc = 0; nc < 4; nc++)
    #pragma unroll
    for (int r = 0; r < 4; r++) {
      int row = i0 + band + q * 4 + r;
      size_t gi = (size_t)(b * S_LEN + row) * E_DIM + h * HD + nc * 16 + fr;
      GQ[gi] = f2bu(dqacc[nc][r]);
    }
}

// ---- bwd dk/dv: ST=K*Q^T, dPT=V*G^T; PT/dST->LDS; dv=PT*G^T(Gt), dk=dST*Q^T(Qt) ----
__global__ __launch_bounds__(256) void bwd_kv(const ushort_t* __restrict__ Qg,
                                              const ushort_t* __restrict__ Kg,
                                              const ushort_t* __restrict__ Vg,
                                              const ushort_t* __restrict__ Gg,
                                              const ushort_t* __restrict__ Qt,
                                              const ushort_t* __restrict__ Gt,
                                              const float* __restrict__ mbuf,
                                              const float* __restrict__ lbuf,
                                              const float* __restrict__ Dv,
                                              ushort_t* __restrict__ GK,
                                              ushort_t* __restrict__ GV) {
  int jt = blockIdx.x;  // jt=0 heaviest, dispatched first
  int bh = blockIdx.y, b = bh >> 4, h = bh & 15;
  int tid = threadIdx.x, lane = tid & 63, wv = tid >> 6;
  int fr = lane & 15, q = lane >> 4;
  int j0 = jt * 64, band = wv * 16;
  __shared__ ushort_t Qs_[64][72];  // [i][d]
  __shared__ ushort_t Gs_[64][72];  // [i][d]
  __shared__ ushort_t Qtt[64][72];  // [d][i]
  __shared__ ushort_t Gtt[64][72];  // [d][i]
  __shared__ ushort_t PT[64][72];   // [j][i]
  __shared__ ushort_t dST[64][72];  // [j][i]

  const ushort_t* Krow = Kg + (size_t)(b * S_LEN + j0 + band + fr) * E_DIM + h * HD;
  const ushort_t* Vrow = Vg + (size_t)(b * S_LEN + j0 + band + fr) * E_DIM + h * HD;
  bf16x8 ak0 = ldg8(Krow + q * 8), ak1 = ldg8(Krow + 32 + q * 8);
  bf16x8 av0 = ldg8(Vrow + q * 8), av1 = ldg8(Vrow + 32 + q * 8);

  f32x4 dkacc[4] = {}, dvacc[4] = {};

  #pragma unroll 1
  for (int i_t = jt; i_t < 16; i_t++) {
    int i0 = i_t * 64;
    __syncthreads();
    #pragma unroll
    for (int t = 0; t < 2; t++) {
      int u = tid + 256 * t;
      int r = u >> 3, c8 = (u & 7) * 8;
      *(uint4*)&Qs_[r][c8] = *(const uint4*)(Qg + (size_t)(b * S_LEN + i0 + r) * E_DIM + h * HD + c8);
      *(uint4*)&Gs_[r][c8] = *(const uint4*)(Gg + (size_t)(b * S_LEN + i0 + r) * E_DIM + h * HD + c8);
      *(uint4*)&Qtt[r][c8] = *(const uint4*)(Qt + (size_t)(bh * HD + r) * S_LEN + i0 + c8);
      *(uint4*)&Gtt[r][c8] = *(const uint4*)(Gt + (size_t)(bh * HD + r) * S_LEN + i0 + c8);
    }
    __syncthreads();
    float mc[4], lc[4], Dc[4];
    #pragma unroll
    for (int nc = 0; nc < 4; nc++) {
      size_t sid = (size_t)bh * S_LEN + i0 + nc * 16 + fr;
      mc[nc] = mbuf[sid]; lc[nc] = lbuf[sid]; Dc[nc] = Dv[sid];
    }
    f32x4 stA[4], dptA[4];
    #pragma unroll
    for (int nc = 0; nc < 4; nc++) {
      bf16x8 bq0 = *(const bf16x8*)&Qs_[nc * 16 + fr][q * 8];
      bf16x8 bq1 = *(const bf16x8*)&Qs_[nc * 16 + fr][32 + q * 8];
      bf16x8 bg0 = *(const bf16x8*)&Gs_[nc * 16 + fr][q * 8];
      bf16x8 bg1 = *(const bf16x8*)&Gs_[nc * 16 + fr][32 + q * 8];
      f32x4 z = {};
      z = __builtin_amdgcn_mfma_f32_16x16x32_bf16(ak0, bq0, z, 0, 0, 0);
      stA[nc] = __builtin_amdgcn_mfma_f32_16x16x32_bf16(ak1, bq1, z, 0, 0, 0);
      f32x4 z2 = {};
      z2 = __builtin_amdgcn_mfma_f32_16x16x32_bf16(av0, bg0, z2, 0, 0, 0);
      dptA[nc] = __builtin_amdgcn_mfma_f32_16x16x32_bf16(av1, bg1, z2, 0, 0, 0);
    }
    #pragma unroll
    for (int nc = 0; nc < 4; nc++)
      #pragma unroll
      for (int r = 0; r < 4; r++) {
        int jrow = j0 + band + q * 4 + r;
        int icol = i0 + nc * 16 + fr;
        float P = 0.f, ds = 0.f;
        if (icol >= jrow) {
          P = __expf(stA[nc][r] * SC_C - mc[nc]) * lc[nc];
          ds = P * (dptA[nc][r] - Dc[nc]) * SC_C;
        }
        PT[band + q * 4 + r][nc * 16 + fr] = f2bu(P);   // wave-private
        dST[band + q * 4 + r][nc * 16 + fr] = f2bu(ds);
      }
    bf16x8 ap0 = *(const bf16x8*)&PT[band + fr][q * 8];
    bf16x8 ap1 = *(const bf16x8*)&PT[band + fr][32 + q * 8];
    bf16x8 ad0 = *(const bf16x8*)&dST[band + fr][q * 8];
    bf16x8 ad1 = *(const bf16x8*)&dST[band + fr][32 + q * 8];
    #pragma unroll
    for (int nc = 0; nc < 4; nc++) {
      bf16x8 bg0 = *(const bf16x8*)&Gtt[nc * 16 + fr][q * 8];
      bf16x8 bg1 = *(const bf16x8*)&Gtt[nc * 16 + fr][32 + q * 8];
      bf16x8 bq0 = *(const bf16x8*)&Qtt[nc * 16 + fr][q * 8];
      bf16x8 bq1 = *(const bf16x8*)&Qtt[nc * 16 + fr][32 + q * 8];
      dvacc[nc] = __builtin_amdgcn_mfma_f32_16x16x32_bf16(ap0, bg0, dvacc[nc], 0, 0, 0);
      dvacc[nc] = __builtin_amdgcn_mfma_f32_16x16x32_bf16(ap1, bg1, dvacc[nc], 0, 0, 0);
      dkacc[nc] = __builtin_amdgcn_mfma_f32_16x16x32_bf16(ad0, bq0, dkacc[nc], 0, 0, 0);
      dkacc[nc] = __builtin_amdgcn_mfma_f32_16x16x32_bf16(ad1, bq1, dkacc[nc], 0, 0, 0);
    }
  }
  #pragma unroll
  for (int nc = 0; nc < 4; nc++)
    #pragma unroll
    for (int r = 0; r < 4; r++) {
      int jrow = j0 + band + q * 4 + r;
      size_t gi = (size_t)(b * S_LEN + jrow) * E_DIM + h * HD + nc * 16 + fr;
      GK[gi] = f2bu(dkacc[nc][r]);
      GV[gi] = f2bu(dvacc[nc][r]);
    }
}

// ---------------- launch ----------------
extern "C" void kernel_launch(void* const* d_in, const int* in_sizes, int n_in,
                              void* d_out, int out_size, void* d_ws, size_t ws_size,
                              hipStream_t stream) {
  const float* T1 = (const float*)d_in[0];
  const float* Wq = (const float*)d_in[1];
  const float* Wk = (const float*)d_in[2];
  const float* Wv = (const float*)d_in[3];
  const float* Wo = (const float*)d_in[4];

  const size_t M2 = 2097152;   // 2048*1024
  const size_t M1 = 1048576;
  float* w = (float*)d_ws;
  float* Xs = w;                       // 8 MB fp32 target
  float* mS = Xs + M2;                 // 64K f32
  float* lS = mS + 65536;
  float* DvS = lS + 65536;
  ushort_t* u = (ushort_t*)(DvS + 65536);
  ushort_t* W0 = u;          ushort_t* W1 = W0 + M1;  ushort_t* W2 = W1 + M1;
  ushort_t* W3 = W2 + M1;    ushort_t* W4 = W3 + M1;  ushort_t* W5 = W4 + M1;
  ushort_t* Qb = W5 + M1;    ushort_t* Kb = Qb + M2;  ushort_t* Vb = Kb + M2;
  ushort_t* Qt = Vb + M2;    ushort_t* Kt = Qt + M2;  ushort_t* Vt = Kt + M2;
  ushort_t* Gt = Vt + M2;
  ushort_t* Gb = Gt + M2;
  ushort_t* GQb = Gb + M2;   ushort_t* GKb = GQb + M2; ushort_t* GVb = GKb + M2;
  ushort_t* X2b = GVb + M2;
  ushort_t* Rb = GQb;        // stage-1 aliases
  ushort_t* Xsb = GKb;
  float* X2 = (float*)d_out;

  hipMemsetAsync(Xs, 0, M2 * sizeof(float), stream);
  hipMemsetAsync(Xsb, 0, M2 * sizeof(ushort_t), stream);
  hipMemsetAsync(X2, 0, M2 * sizeof(float), stream);
  hipMemsetAsync(X2b, 0, M2 * sizeof(ushort_t), stream);

  dim3 pgrid(16, 16);
  dim3 ggrid(8, 32);
  dim3 ggrid3(8, 32, 3);
  dim3 agrid(16, BH_CNT);

  // ---- stage 1 ----
  prep_w<<<pgrid, 256, 0, stream>>>(Wo, W0, W1);
  for (int t = 0; t < 3; t++) {
    gemm_mf<1, 1><<<ggrid, 256, 0, stream>>>(Xsb, nullptr, nullptr, W0, nullptr, nullptr,
                                             nullptr, T1, Rb, nullptr, nullptr,
                                             nullptr, nullptr, nullptr, 0.f);
    gemm_mf<2, 1><<<ggrid, 256, 0, stream>>>(Rb, nullptr, nullptr, W1, nullptr, nullptr,
                                             Xs, nullptr, Xsb, nullptr, nullptr,
                                             nullptr, nullptr, nullptr, LR_C);
  }
  prep_w<<<pgrid, 256, 0, stream>>>(Wq, W0, W3);
  prep_w<<<pgrid, 256, 0, stream>>>(Wk, W1, W4);
  prep_w<<<pgrid, 256, 0, stream>>>(Wv, W2, W5);

  // ---- stage 2 ----
  for (int t = 0; t < 3; t++) {
    // QKV projection: emits row-major bf16 AND per-head-transposed bf16 (tr_head eliminated)
    gemm_mf<0, 1><<<ggrid3, 256, 0, stream>>>(X2b, nullptr, nullptr, W0, W1, W2,
                                              nullptr, nullptr, Qb, Kb, Vb,
                                              Qt, Kt, Vt, 0.f);
    fwd_fused<<<agrid, 256, 0, stream>>>(Qb, Kb, Vt, Xs, mS, lS, Gb, Gt, DvS);
    bwd_q<<<agrid, 256, 0, stream>>>(Qb, Kb, Vb, Gb, Kt, mS, lS, DvS, GQb);
    bwd_kv<<<agrid, 256, 0, stream>>>(Qb, Kb, Vb, Gb, Qt, Gt, mS, lS, DvS, GKb, GVb);
    gemm_mf<2, 3><<<ggrid, 256, 0, stream>>>(GQb, GKb, GVb, W3, W4, W5,
                                             X2, nullptr, X2b, nullptr, nullptr,
                                             nullptr, nullptr, nullptr, -LR_C);
  }
}

// Round 9
// 780.758 us; speedup vs baseline: 1.4046x; 1.1287x over previous
//
#include <hip/hip_runtime.h>
#include <hip/hip_bf16.h>

// Problem constants (B=2, S=1024, E=1024, H=16, D=64)
#define S_LEN 1024
#define E_DIM 1024
#define NH 16
#define HD 64
#define M_ROWS 2048   // B*S
#define BH_CNT 32     // B*NH

static constexpr float LR_C = 0.01f;
static constexpr float SC_C = 0.125f;  // 1/sqrt(64)

typedef unsigned short ushort_t;
typedef __attribute__((ext_vector_type(8))) __bf16 bf16x8;
typedef __attribute__((ext_vector_type(4))) float f32x4;

static __device__ inline ushort_t f2bu(float f) {
  __hip_bfloat16 h = __float2bfloat16(f);
  return *(ushort_t*)&h;
}
static __device__ inline bf16x8 ldg8(const ushort_t* p) { return *(const bf16x8*)p; }

// ---------------- weight prep: bf16 cast + bf16 transpose, 64x64 tiles ----------------
__global__ __launch_bounds__(256) void prep_w(const float* __restrict__ W,
                                              ushort_t* __restrict__ Wb,
                                              ushort_t* __restrict__ WTb) {
  __shared__ float ts[64][65];
  int bx = blockIdx.x * 64, by = blockIdx.y * 64;
  int t = threadIdx.x;
  int rr = t >> 6, cc = t & 63;
  #pragma unroll
  for (int p = 0; p < 16; p++) {
    int r = p * 4 + rr;
    float v = W[(size_t)(by + r) * E_DIM + bx + cc];
    ts[r][cc] = v;
    Wb[(size_t)(by + r) * E_DIM + bx + cc] = f2bu(v);
  }
  __syncthreads();
  #pragma unroll
  for (int p = 0; p < 16; p++) {
    int r = p * 4 + rr;
    WTb[(size_t)(bx + r) * E_DIM + by + cc] = f2bu(ts[cc][r]);
  }
}

// ---------------- bf16 MFMA GEMM: C[2048,1024] = A[M,K=1024] * B[N,K]^T ----------------
// MODE 0: Cb_z = bf16(acc), and Ct_z = per-head-transposed bf16 [bh][d][token]  [QKV proj]
// MODE 1: Cb0 = bf16(T - acc)                                                  [stage-1 residual]
// MODE 2: Cf += alpha*acc (fp32) and Cb0 = bf16(Cf), NSEG K-segments           [PC update]
template <int MODE, int NSEG>
__global__ __launch_bounds__(256) void gemm_mf(
    const ushort_t* __restrict__ A0, const ushort_t* __restrict__ A1, const ushort_t* __restrict__ A2,
    const ushort_t* __restrict__ B0, const ushort_t* __restrict__ B1, const ushort_t* __restrict__ B2,
    float* __restrict__ Cf, const float* __restrict__ T,
    ushort_t* __restrict__ Cb0, ushort_t* __restrict__ Cb1, ushort_t* __restrict__ Cb2,
    ushort_t* __restrict__ Ct0, ushort_t* __restrict__ Ct1, ushort_t* __restrict__ Ct2,
    float alpha) {
  const int K = 1024;
  __shared__ __bf16 As[64][40];
  __shared__ __bf16 Bs[128][40];
  int tid = threadIdx.x;
  int m0 = blockIdx.y * 64, n0 = blockIdx.x * 128;

  const ushort_t* Bsel = B0;
  ushort_t* Cbz = Cb0;
  ushort_t* Ctz = Ct0;
  if (MODE == 0) {
    int z = blockIdx.z;
    Bsel = (z == 0) ? B0 : (z == 1) ? B1 : B2;
    Cbz = (z == 0) ? Cb0 : (z == 1) ? Cb1 : Cb2;
    Ctz = (z == 0) ? Ct0 : (z == 1) ? Ct1 : Ct2;
  }

  int lane = tid & 63, wave = tid >> 6;
  int wrow = wave >> 1, wcol = wave & 1;
  int fr = lane & 15, q = lane >> 4;

  f32x4 acc[2][4] = {};

  int ar = tid >> 2, ac = (tid & 3) * 8;
  #pragma unroll 1
  for (int seg = 0; seg < NSEG; seg++) {
    const ushort_t* Aseg = (seg == 0) ? A0 : (seg == 1) ? A1 : A2;
    const ushort_t* Bseg = (MODE == 0) ? Bsel : ((seg == 0) ? B0 : (seg == 1) ? B1 : B2);
    const ushort_t* Ag = Aseg + (size_t)(m0 + ar) * K + ac;
    const ushort_t* Bg0 = Bseg + (size_t)(n0 + ar) * K + ac;
    const ushort_t* Bg1 = Bseg + (size_t)(n0 + 64 + ar) * K + ac;
    for (int k0 = 0; k0 < K; k0 += 32) {
      uint4 av = *(const uint4*)(Ag + k0);
      uint4 bv0 = *(const uint4*)(Bg0 + k0);
      uint4 bv1 = *(const uint4*)(Bg1 + k0);
      __syncthreads();
      *(uint4*)&As[ar][ac] = av;
      *(uint4*)&Bs[ar][ac] = bv0;
      *(uint4*)&Bs[64 + ar][ac] = bv1;
      __syncthreads();
      bf16x8 a0 = *(const bf16x8*)&As[wrow * 32 + fr][q * 8];
      bf16x8 a1 = *(const bf16x8*)&As[wrow * 32 + 16 + fr][q * 8];
      bf16x8 b0 = *(const bf16x8*)&Bs[wcol * 64 + fr][q * 8];
      bf16x8 b1 = *(const bf16x8*)&Bs[wcol * 64 + 16 + fr][q * 8];
      bf16x8 b2 = *(const bf16x8*)&Bs[wcol * 64 + 32 + fr][q * 8];
      bf16x8 b3 = *(const bf16x8*)&Bs[wcol * 64 + 48 + fr][q * 8];
      acc[0][0] = __builtin_amdgcn_mfma_f32_16x16x32_bf16(a0, b0, acc[0][0], 0, 0, 0);
      acc[0][1] = __builtin_amdgcn_mfma_f32_16x16x32_bf16(a0, b1, acc[0][1], 0, 0, 0);
      acc[0][2] = __builtin_amdgcn_mfma_f32_16x16x32_bf16(a0, b2, acc[0][2], 0, 0, 0);
      acc[0][3] = __builtin_amdgcn_mfma_f32_16x16x32_bf16(a0, b3, acc[0][3], 0, 0, 0);
      acc[1][0] = __builtin_amdgcn_mfma_f32_16x16x32_bf16(a1, b0, acc[1][0], 0, 0, 0);
      acc[1][1] = __builtin_amdgcn_mfma_f32_16x16x32_bf16(a1, b1, acc[1][1], 0, 0, 0);
      acc[1][2] = __builtin_amdgcn_mfma_f32_16x16x32_bf16(a1, b2, acc[1][2], 0, 0, 0);
      acc[1][3] = __builtin_amdgcn_mfma_f32_16x16x32_bf16(a1, b3, acc[1][3], 0, 0, 0);
    }
  }

  // C/D layout: col = lane&15, row = (lane>>4)*4 + reg
  #pragma unroll
  for (int mi = 0; mi < 2; mi++)
    #pragma unroll
    for (int ni = 0; ni < 4; ni++) {
      int col = n0 + wcol * 64 + ni * 16 + fr;
      int row0 = m0 + wrow * 32 + mi * 16 + q * 4;
      ushort_t pk[4];
      #pragma unroll
      for (int r = 0; r < 4; r++) {
        size_t idx = (size_t)(row0 + r) * E_DIM + col;
        float v = acc[mi][ni][r];
        if (MODE == 0) {
          ushort_t bu = f2bu(v);
          pk[r] = bu;
          Cbz[idx] = bu;
        } else if (MODE == 1) {
          Cb0[idx] = f2bu(T[idx] - v);
        } else {
          float nv = Cf[idx] + alpha * v;
          Cf[idx] = nv;
          Cb0[idx] = f2bu(nv);
        }
      }
      if (MODE == 0) {
        // transposed write: Xt[(b*16+h)*64 + d][token], 4 consecutive tokens -> one 8B store
        int hh = col >> 6, dd = col & 63;
        int bb = row0 >> 10, ss = row0 & 1023;
        *(uint2*)(Ctz + ((size_t)((bb * NH + hh) * HD + dd)) * S_LEN + ss) = *(uint2*)pk;
      }
    }
}

// ====================== MFMA attention, LDS-staged ======================
// Balanced causal dispatch: grid (bh=32, y=16); co-resident blocks (n, n+256) get
// complementary tile pairs summing to 17 work-units per CU (in-order round-robin).

// ---- fused fwd: single-pass flash, online softmax; emits m, 1/l, g=O-Xs (bf16 + transposed), Dv ----
__global__ __launch_bounds__(256) void fwd_fused(const ushort_t* __restrict__ Qg,
                                                 const ushort_t* __restrict__ Kg,
                                                 const ushort_t* __restrict__ Vt,
                                                 const float* __restrict__ Xs,
                                                 float* __restrict__ mbuf,
                                                 float* __restrict__ lbuf,
                                                 ushort_t* __restrict__ Gb,
                                                 ushort_t* __restrict__ Gt,
                                                 float* __restrict__ Dv) {
  int bh = blockIdx.x, y = blockIdx.y;
  int it = (y < 8) ? (15 - y) : (y - 8);   // pair (16-y) + (y+1) = 17 units/CU
  int b = bh >> 4, h = bh & 15;
  int tid = threadIdx.x, lane = tid & 63, wv = tid >> 6;
  int fr = lane & 15, q = lane >> 4;
  int i0 = it * 64, band = wv * 16;
  __shared__ ushort_t Kts[64][72];  // [j][d]
  __shared__ ushort_t Vts[64][72];  // [d][j]
  __shared__ ushort_t Ps[64][72];   // [i][j] wave-private bands

  const ushort_t* Qrow = Qg + (size_t)(b * S_LEN + i0 + band + fr) * E_DIM + h * HD;
  bf16x8 aq0 = ldg8(Qrow + q * 8);
  bf16x8 aq1 = ldg8(Qrow + 32 + q * 8);

  float m[4], l[4];
  #pragma unroll
  for (int r = 0; r < 4; r++) { m[r] = -1e30f; l[r] = 0.f; }
  f32x4 oacc[4] = {};

  #pragma unroll 1
  for (int jt = 0; jt <= it; jt++) {
    int j0 = jt * 64;
    __syncthreads();
    #pragma unroll
    for (int t = 0; t < 2; t++) {
      int u = tid + 256 * t;
      int r = u >> 3, c8 = (u & 7) * 8;
      *(uint4*)&Kts[r][c8] = *(const uint4*)(Kg + (size_t)(b * S_LEN + j0 + r) * E_DIM + h * HD + c8);
      *(uint4*)&Vts[r][c8] = *(const uint4*)(Vt + (size_t)(bh * HD + r) * S_LEN + j0 + c8);
    }
    __syncthreads();
    f32x4 sA[4];
    #pragma unroll
    for (int nc = 0; nc < 4; nc++) {
      bf16x8 bk0 = *(const bf16x8*)&Kts[nc * 16 + fr][q * 8];
      bf16x8 bk1 = *(const bf16x8*)&Kts[nc * 16 + fr][32 + q * 8];
      f32x4 z = {};
      z = __builtin_amdgcn_mfma_f32_16x16x32_bf16(aq0, bk0, z, 0, 0, 0);
      sA[nc] = __builtin_amdgcn_mfma_f32_16x16x32_bf16(aq1, bk1, z, 0, 0, 0);
    }
    float sv[4][4];
    #pragma unroll
    for (int nc = 0; nc < 4; nc++)
      #pragma unroll
      for (int r = 0; r < 4; r++) {
        int row = i0 + band + q * 4 + r;
        int col = j0 + nc * 16 + fr;
        sv[nc][r] = (col <= row) ? sA[nc][r] * SC_C : -1e30f;
      }
    #pragma unroll
    for (int r = 0; r < 4; r++) {
      float mx = fmaxf(fmaxf(sv[0][r], sv[1][r]), fmaxf(sv[2][r], sv[3][r]));
      #pragma unroll
      for (int off = 1; off < 16; off <<= 1) mx = fmaxf(mx, __shfl_xor(mx, off, 64));
      float mn = fmaxf(m[r], mx);
      float alpha = __expf(m[r] - mn);
      float ps = 0.f;
      #pragma unroll
      for (int nc = 0; nc < 4; nc++) {
        float p = __expf(sv[nc][r] - mn);
        Ps[band + q * 4 + r][nc * 16 + fr] = f2bu(p);
        ps += p;
      }
      #pragma unroll
      for (int off = 1; off < 16; off <<= 1) ps += __shfl_xor(ps, off, 64);
      l[r] = l[r] * alpha + ps;
      m[r] = mn;
      #pragma unroll
      for (int nc = 0; nc < 4; nc++) oacc[nc][r] *= alpha;
    }
    bf16x8 ap0 = *(const bf16x8*)&Ps[band + fr][q * 8];
    bf16x8 ap1 = *(const bf16x8*)&Ps[band + fr][32 + q * 8];
    #pragma unroll
    for (int nc = 0; nc < 4; nc++) {
      bf16x8 bv0 = *(const bf16x8*)&Vts[nc * 16 + fr][q * 8];
      bf16x8 bv1 = *(const bf16x8*)&Vts[nc * 16 + fr][32 + q * 8];
      oacc[nc] = __builtin_amdgcn_mfma_f32_16x16x32_bf16(ap0, bv0, oacc[nc], 0, 0, 0);
      oacc[nc] = __builtin_amdgcn_mfma_f32_16x16x32_bf16(ap1, bv1, oacc[nc], 0, 0, 0);
    }
  }
  // epilogue: g = O - Xs (bf16 normal + transposed), Dv partials
  float linv[4];
  #pragma unroll
  for (int r = 0; r < 4; r++) linv[r] = 1.0f / l[r];
  float dpart[4] = {};
  #pragma unroll
  for (int nc = 0; nc < 4; nc++) {
    ushort_t pg[4];
    #pragma unroll
    for (int r = 0; r < 4; r++) {
      int row = i0 + band + q * 4 + r;
      size_t gi = (size_t)(b * S_LEN + row) * E_DIM + h * HD + nc * 16 + fr;
      float o = oacc[nc][r] * linv[r];
      float g = o - Xs[gi];
      ushort_t bu = f2bu(g);
      Gb[gi] = bu;
      pg[r] = bu;
      dpart[r] += g * o;
    }
    int d = nc * 16 + fr;
    int s0 = i0 + band + q * 4;
    *(uint2*)(Gt + ((size_t)bh * HD + d) * S_LEN + s0) = *(uint2*)pg;
  }
  #pragma unroll
  for (int r = 0; r < 4; r++) {
    #pragma unroll
    for (int off = 1; off < 16; off <<= 1) dpart[r] += __shfl_xor(dpart[r], off, 64);
  }
  if (fr == 0) {
    #pragma unroll
    for (int r = 0; r < 4; r++) {
      size_t sid = (size_t)bh * S_LEN + i0 + band + q * 4 + r;
      mbuf[sid] = m[r];
      lbuf[sid] = linv[r];
      Dv[sid] = dpart[r];
    }
  }
}

// ---- bwd dq: S=QK^T, dP=GV^T, dS->LDS, dq = dS*K^T (Kt tile) ----
__global__ __launch_bounds__(256) void bwd_q(const ushort_t* __restrict__ Qg,
                                             const ushort_t* __restrict__ Kg,
                                             const ushort_t* __restrict__ Vg,
                                             const ushort_t* __restrict__ Gg,
                                             const ushort_t* __restrict__ Kt,
                                             const float* __restrict__ mbuf,
                                             const float* __restrict__ lbuf,
                                             const float* __restrict__ Dv,
                                             ushort_t* __restrict__ GQ) {
  int bh = blockIdx.x, y = blockIdx.y;
  int it = (y < 8) ? (15 - y) : (y - 8);   // balanced pairs
  int b = bh >> 4, h = bh & 15;
  int tid = threadIdx.x, lane = tid & 63, wv = tid >> 6;
  int fr = lane & 15, q = lane >> 4;
  int i0 = it * 64, band = wv * 16;
  __shared__ ushort_t Kts[64][72];   // [j][d]
  __shared__ ushort_t Vts[64][72];   // [j][d]
  __shared__ ushort_t Ktt[64][72];   // [d][j]
  __shared__ ushort_t dSs[64][72];

  const ushort_t* Qrow = Qg + (size_t)(b * S_LEN + i0 + band + fr) * E_DIM + h * HD;
  const ushort_t* Grow = Gg + (size_t)(b * S_LEN + i0 + band + fr) * E_DIM + h * HD;
  bf16x8 aq0 = ldg8(Qrow + q * 8), aq1 = ldg8(Qrow + 32 + q * 8);
  bf16x8 ag0 = ldg8(Grow + q * 8), ag1 = ldg8(Grow + 32 + q * 8);

  float mrow[4], linv[4], Dr[4];
  #pragma unroll
  for (int r = 0; r < 4; r++) {
    size_t sid = (size_t)bh * S_LEN + i0 + band + q * 4 + r;
    mrow[r] = mbuf[sid]; linv[r] = lbuf[sid]; Dr[r] = Dv[sid];
  }
  f32x4 dqacc[4] = {};

  #pragma unroll 1
  for (int jt = 0; jt <= it; jt++) {
    int j0 = jt * 64;
    __syncthreads();
    #pragma unroll
    for (int t = 0; t < 2; t++) {
      int u = tid + 256 * t;
      int r = u >> 3, c8 = (u & 7) * 8;
      *(uint4*)&Kts[r][c8] = *(const uint4*)(Kg + (size_t)(b * S_LEN + j0 + r) * E_DIM + h * HD + c8);
      *(uint4*)&Vts[r][c8] = *(const uint4*)(Vg + (size_t)(b * S_LEN + j0 + r) * E_DIM + h * HD + c8);
      *(uint4*)&Ktt[r][c8] = *(const uint4*)(Kt + (size_t)(bh * HD + r) * S_LEN + j0 + c8);
    }
    __syncthreads();
    f32x4 sA[4], dpA[4];
    #pragma unroll
    for (int nc = 0; nc < 4; nc++) {
      bf16x8 bk0 = *(const bf16x8*)&Kts[nc * 16 + fr][q * 8];
      bf16x8 bk1 = *(const bf16x8*)&Kts[nc * 16 + fr][32 + q * 8];
      bf16x8 bv0 = *(const bf16x8*)&Vts[nc * 16 + fr][q * 8];
      bf16x8 bv1 = *(const bf16x8*)&Vts[nc * 16 + fr][32 + q * 8];
      f32x4 z = {};
      z = __builtin_amdgcn_mfma_f32_16x16x32_bf16(aq0, bk0, z, 0, 0, 0);
      sA[nc] = __builtin_amdgcn_mfma_f32_16x16x32_bf16(aq1, bk1, z, 0, 0, 0);
      f32x4 z2 = {};
      z2 = __builtin_amdgcn_mfma_f32_16x16x32_bf16(ag0, bv0, z2, 0, 0, 0);
      dpA[nc] = __builtin_amdgcn_mfma_f32_16x16x32_bf16(ag1, bv1, z2, 0, 0, 0);
    }
    #pragma unroll
    for (int nc = 0; nc < 4; nc++)
      #pragma unroll
      for (int r = 0; r < 4; r++) {
        int row = i0 + band + q * 4 + r;
        int col = j0 + nc * 16 + fr;
        float ds = 0.f;
        if (col <= row) {
          float P = __expf(sA[nc][r] * SC_C - mrow[r]) * linv[r];
          ds = P * (dpA[nc][r] - Dr[r]) * SC_C;
        }
        dSs[band + q * 4 + r][nc * 16 + fr] = f2bu(ds);  // wave-private
      }
    bf16x8 ad0 = *(const bf16x8*)&dSs[band + fr][q * 8];
    bf16x8 ad1 = *(const bf16x8*)&dSs[band + fr][32 + q * 8];
    #pragma unroll
    for (int nc = 0; nc < 4; nc++) {
      bf16x8 bt0 = *(const bf16x8*)&Ktt[nc * 16 + fr][q * 8];
      bf16x8 bt1 = *(const bf16x8*)&Ktt[nc * 16 + fr][32 + q * 8];
      dqacc[nc] = __builtin_amdgcn_mfma_f32_16x16x32_bf16(ad0, bt0, dqacc[nc], 0, 0, 0);
      dqacc[nc] = __builtin_amdgcn_mfma_f32_16x16x32_bf16(ad1, bt1, dqacc[nc], 0, 0, 0);
    }
  }
  #pragma unroll
  for (int nc = 0; nc < 4; nc++)
    #pragma unroll
    for (int r = 0; r < 4; r++) {
      int row = i0 + band + q * 4 + r;
      size_t gi = (size_t)(b * S_LEN + row) * E_DIM + h * HD + nc * 16 + fr;
      GQ[gi] = f2bu(dqacc[nc][r]);
    }
}

// ---- bwd dk/dv: ST=K*Q^T, dPT=V*G^T; PT/dST->LDS; dv=PT*G^T(Gt), dk=dST*Q^T(Qt) ----
__global__ __launch_bounds__(256) void bwd_kv(const ushort_t* __restrict__ Qg,
                                              const ushort_t* __restrict__ Kg,
                                              const ushort_t* __restrict__ Vg,
                                              const ushort_t* __restrict__ Gg,
                                              const ushort_t* __restrict__ Qt,
                                              const ushort_t* __restrict__ Gt,
                                              const float* __restrict__ mbuf,
                                              const float* __restrict__ lbuf,
                                              const float* __restrict__ Dv,
                                              ushort_t* __restrict__ GK,
                                              ushort_t* __restrict__ GV) {
  int bh = blockIdx.x, y = blockIdx.y;
  int jt = (y < 8) ? y : (23 - y);   // pair (16-y) + (1+y) = 17 units/CU
  int b = bh >> 4, h = bh & 15;
  int tid = threadIdx.x, lane = tid & 63, wv = tid >> 6;
  int fr = lane & 15, q = lane >> 4;
  int j0 = jt * 64, band = wv * 16;
  __shared__ ushort_t Qs_[64][72];  // [i][d]
  __shared__ ushort_t Gs_[64][72];  // [i][d]
  __shared__ ushort_t Qtt[64][72];  // [d][i]
  __shared__ ushort_t Gtt[64][72];  // [d][i]
  __shared__ ushort_t PT[64][72];   // [j][i]
  __shared__ ushort_t dST[64][72];  // [j][i]

  const ushort_t* Krow = Kg + (size_t)(b * S_LEN + j0 + band + fr) * E_DIM + h * HD;
  const ushort_t* Vrow = Vg + (size_t)(b * S_LEN + j0 + band + fr) * E_DIM + h * HD;
  bf16x8 ak0 = ldg8(Krow + q * 8), ak1 = ldg8(Krow + 32 + q * 8);
  bf16x8 av0 = ldg8(Vrow + q * 8), av1 = ldg8(Vrow + 32 + q * 8);

  f32x4 dkacc[4] = {}, dvacc[4] = {};

  #pragma unroll 1
  for (int i_t = jt; i_t < 16; i_t++) {
    int i0 = i_t * 64;
    __syncthreads();
    #pragma unroll
    for (int t = 0; t < 2; t++) {
      int u = tid + 256 * t;
      int r = u >> 3, c8 = (u & 7) * 8;
      *(uint4*)&Qs_[r][c8] = *(const uint4*)(Qg + (size_t)(b * S_LEN + i0 + r) * E_DIM + h * HD + c8);
      *(uint4*)&Gs_[r][c8] = *(const uint4*)(Gg + (size_t)(b * S_LEN + i0 + r) * E_DIM + h * HD + c8);
      *(uint4*)&Qtt[r][c8] = *(const uint4*)(Qt + (size_t)(bh * HD + r) * S_LEN + i0 + c8);
      *(uint4*)&Gtt[r][c8] = *(const uint4*)(Gt + (size_t)(bh * HD + r) * S_LEN + i0 + c8);
    }
    __syncthreads();
    float mc[4], lc[4], Dc[4];
    #pragma unroll
    for (int nc = 0; nc < 4; nc++) {
      size_t sid = (size_t)bh * S_LEN + i0 + nc * 16 + fr;
      mc[nc] = mbuf[sid]; lc[nc] = lbuf[sid]; Dc[nc] = Dv[sid];
    }
    f32x4 stA[4], dptA[4];
    #pragma unroll
    for (int nc = 0; nc < 4; nc++) {
      bf16x8 bq0 = *(const bf16x8*)&Qs_[nc * 16 + fr][q * 8];
      bf16x8 bq1 = *(const bf16x8*)&Qs_[nc * 16 + fr][32 + q * 8];
      bf16x8 bg0 = *(const bf16x8*)&Gs_[nc * 16 + fr][q * 8];
      bf16x8 bg1 = *(const bf16x8*)&Gs_[nc * 16 + fr][32 + q * 8];
      f32x4 z = {};
      z = __builtin_amdgcn_mfma_f32_16x16x32_bf16(ak0, bq0, z, 0, 0, 0);
      stA[nc] = __builtin_amdgcn_mfma_f32_16x16x32_bf16(ak1, bq1, z, 0, 0, 0);
      f32x4 z2 = {};
      z2 = __builtin_amdgcn_mfma_f32_16x16x32_bf16(av0, bg0, z2, 0, 0, 0);
      dptA[nc] = __builtin_amdgcn_mfma_f32_16x16x32_bf16(av1, bg1, z2, 0, 0, 0);
    }
    #pragma unroll
    for (int nc = 0; nc < 4; nc++)
      #pragma unroll
      for (int r = 0; r < 4; r++) {
        int jrow = j0 + band + q * 4 + r;
        int icol = i0 + nc * 16 + fr;
        float P = 0.f, ds = 0.f;
        if (icol >= jrow) {
          P = __expf(stA[nc][r] * SC_C - mc[nc]) * lc[nc];
          ds = P * (dptA[nc][r] - Dc[nc]) * SC_C;
        }
        PT[band + q * 4 + r][nc * 16 + fr] = f2bu(P);   // wave-private
        dST[band + q * 4 + r][nc * 16 + fr] = f2bu(ds);
      }
    bf16x8 ap0 = *(const bf16x8*)&PT[band + fr][q * 8];
    bf16x8 ap1 = *(const bf16x8*)&PT[band + fr][32 + q * 8];
    bf16x8 ad0 = *(const bf16x8*)&dST[band + fr][q * 8];
    bf16x8 ad1 = *(const bf16x8*)&dST[band + fr][32 + q * 8];
    #pragma unroll
    for (int nc = 0; nc < 4; nc++) {
      bf16x8 bg0 = *(const bf16x8*)&Gtt[nc * 16 + fr][q * 8];
      bf16x8 bg1 = *(const bf16x8*)&Gtt[nc * 16 + fr][32 + q * 8];
      bf16x8 bq0 = *(const bf16x8*)&Qtt[nc * 16 + fr][q * 8];
      bf16x8 bq1 = *(const bf16x8*)&Qtt[nc * 16 + fr][32 + q * 8];
      dvacc[nc] = __builtin_amdgcn_mfma_f32_16x16x32_bf16(ap0, bg0, dvacc[nc], 0, 0, 0);
      dvacc[nc] = __builtin_amdgcn_mfma_f32_16x16x32_bf16(ap1, bg1, dvacc[nc], 0, 0, 0);
      dkacc[nc] = __builtin_amdgcn_mfma_f32_16x16x32_bf16(ad0, bq0, dkacc[nc], 0, 0, 0);
      dkacc[nc] = __builtin_amdgcn_mfma_f32_16x16x32_bf16(ad1, bq1, dkacc[nc], 0, 0, 0);
    }
  }
  #pragma unroll
  for (int nc = 0; nc < 4; nc++)
    #pragma unroll
    for (int r = 0; r < 4; r++) {
      int jrow = j0 + band + q * 4 + r;
      size_t gi = (size_t)(b * S_LEN + jrow) * E_DIM + h * HD + nc * 16 + fr;
      GK[gi] = f2bu(dkacc[nc][r]);
      GV[gi] = f2bu(dvacc[nc][r]);
    }
}

// ---------------- launch ----------------
extern "C" void kernel_launch(void* const* d_in, const int* in_sizes, int n_in,
                              void* d_out, int out_size, void* d_ws, size_t ws_size,
                              hipStream_t stream) {
  const float* T1 = (const float*)d_in[0];
  const float* Wq = (const float*)d_in[1];
  const float* Wk = (const float*)d_in[2];
  const float* Wv = (const float*)d_in[3];
  const float* Wo = (const float*)d_in[4];

  const size_t M2 = 2097152;   // 2048*1024
  const size_t M1 = 1048576;
  float* w = (float*)d_ws;
  float* Xs = w;                       // 8 MB fp32 target
  float* mS = Xs + M2;                 // 64K f32
  float* lS = mS + 65536;
  float* DvS = lS + 65536;
  ushort_t* u = (ushort_t*)(DvS + 65536);
  ushort_t* W0 = u;          ushort_t* W1 = W0 + M1;  ushort_t* W2 = W1 + M1;
  ushort_t* W3 = W2 + M1;    ushort_t* W4 = W3 + M1;  ushort_t* W5 = W4 + M1;
  ushort_t* Qb = W5 + M1;    ushort_t* Kb = Qb + M2;  ushort_t* Vb = Kb + M2;
  ushort_t* Qt = Vb + M2;    ushort_t* Kt = Qt + M2;  ushort_t* Vt = Kt + M2;
  ushort_t* Gt = Vt + M2;
  ushort_t* Gb = Gt + M2;
  ushort_t* GQb = Gb + M2;   ushort_t* GKb = GQb + M2; ushort_t* GVb = GKb + M2;
  ushort_t* X2b = GVb + M2;
  ushort_t* Rb = GQb;        // stage-1 aliases
  ushort_t* Xsb = GKb;
  float* X2 = (float*)d_out;

  hipMemsetAsync(Xs, 0, M2 * sizeof(float), stream);
  hipMemsetAsync(Xsb, 0, M2 * sizeof(ushort_t), stream);
  hipMemsetAsync(X2, 0, M2 * sizeof(float), stream);
  hipMemsetAsync(X2b, 0, M2 * sizeof(ushort_t), stream);

  dim3 pgrid(16, 16);
  dim3 ggrid(8, 32);
  dim3 ggrid3(8, 32, 3);
  dim3 agrid(BH_CNT, 16);   // (bh, y) — balanced causal-tile mapping inside kernels

  // ---- stage 1 ----
  prep_w<<<pgrid, 256, 0, stream>>>(Wo, W0, W1);
  for (int t = 0; t < 3; t++) {
    gemm_mf<1, 1><<<ggrid, 256, 0, stream>>>(Xsb, nullptr, nullptr, W0, nullptr, nullptr,
                                             nullptr, T1, Rb, nullptr, nullptr,
                                             nullptr, nullptr, nullptr, 0.f);
    gemm_mf<2, 1><<<ggrid, 256, 0, stream>>>(Rb, nullptr, nullptr, W1, nullptr, nullptr,
                                             Xs, nullptr, Xsb, nullptr, nullptr,
                                             nullptr, nullptr, nullptr, LR_C);
  }
  prep_w<<<pgrid, 256, 0, stream>>>(Wq, W0, W3);
  prep_w<<<pgrid, 256, 0, stream>>>(Wk, W1, W4);
  prep_w<<<pgrid, 256, 0, stream>>>(Wv, W2, W5);

  // ---- stage 2 ----
  for (int t = 0; t < 3; t++) {
    // QKV projection: emits row-major bf16 AND per-head-transposed bf16
    gemm_mf<0, 1><<<ggrid3, 256, 0, stream>>>(X2b, nullptr, nullptr, W0, W1, W2,
                                              nullptr, nullptr, Qb, Kb, Vb,
                                              Qt, Kt, Vt, 0.f);
    fwd_fused<<<agrid, 256, 0, stream>>>(Qb, Kb, Vt, Xs, mS, lS, Gb, Gt, DvS);
    bwd_q<<<agrid, 256, 0, stream>>>(Qb, Kb, Vb, Gb, Kt, mS, lS, DvS, GQb);
    bwd_kv<<<agrid, 256, 0, stream>>>(Qb, Kb, Vb, Gb, Qt, Gt, mS, lS, DvS, GKb, GVb);
    gemm_mf<2, 3><<<ggrid, 256, 0, stream>>>(GQb, GKb, GVb, W3, W4, W5,
                                             X2, nullptr, X2b, nullptr, nullptr,
                                             nullptr, nullptr, nullptr, -LR_C);
  }
}

// Round 10
// 649.686 us; speedup vs baseline: 1.6880x; 1.2017x over previous
//
#include <hip/hip_runtime.h>
#include <hip/hip_bf16.h>

// Problem constants (B=2, S=1024, E=1024, H=16, D=64)
#define S_LEN 1024
#define E_DIM 1024
#define NH 16
#define HD 64
#define M_ROWS 2048   // B*S
#define BH_CNT 32     // B*NH

static constexpr float LR_C = 0.01f;
static constexpr float SC_C = 0.125f;  // 1/sqrt(64)

typedef unsigned short ushort_t;
typedef __attribute__((ext_vector_type(8))) __bf16 bf16x8;
typedef __attribute__((ext_vector_type(4))) float f32x4;

static __device__ inline ushort_t f2bu(float f) {
  __hip_bfloat16 h = __float2bfloat16(f);
  return *(ushort_t*)&h;
}
static __device__ inline bf16x8 ldg8(const ushort_t* p) { return *(const bf16x8*)p; }

// ---------------- weight prep: bf16 cast + bf16 transpose, 64x64 tiles ----------------
__global__ __launch_bounds__(256) void prep_w(const float* __restrict__ W,
                                              ushort_t* __restrict__ Wb,
                                              ushort_t* __restrict__ WTb) {
  __shared__ float ts[64][65];
  int bx = blockIdx.x * 64, by = blockIdx.y * 64;
  int t = threadIdx.x;
  int rr = t >> 6, cc = t & 63;
  #pragma unroll
  for (int p = 0; p < 16; p++) {
    int r = p * 4 + rr;
    float v = W[(size_t)(by + r) * E_DIM + bx + cc];
    ts[r][cc] = v;
    Wb[(size_t)(by + r) * E_DIM + bx + cc] = f2bu(v);
  }
  __syncthreads();
  #pragma unroll
  for (int p = 0; p < 16; p++) {
    int r = p * 4 + rr;
    WTb[(size_t)(bx + r) * E_DIM + by + cc] = f2bu(ts[cc][r]);
  }
}

// ---------------- bf16 MFMA GEMM, 64x64 tile (2+ blocks/CU): C[2048,1024] = A*B^T ----------------
// grid (16, 32[, 3]).  4 waves in 2x2, each wave 32x32 (2x2 MFMAs).
// MODE 0: Cb_z = bf16(acc) + Ct_z transposed [bh][d][token]   [QKV proj]
// MODE 1: Cb0 = bf16(T - acc)                                 [stage-1 residual]
// MODE 2: Cf += alpha*acc (fp32) and Cb0 = bf16(Cf), NSEG K-segments [PC update]
template <int MODE, int NSEG>
__global__ __launch_bounds__(256) void gemm_mf(
    const ushort_t* __restrict__ A0, const ushort_t* __restrict__ A1, const ushort_t* __restrict__ A2,
    const ushort_t* __restrict__ B0, const ushort_t* __restrict__ B1, const ushort_t* __restrict__ B2,
    float* __restrict__ Cf, const float* __restrict__ T,
    ushort_t* __restrict__ Cb0, ushort_t* __restrict__ Cb1, ushort_t* __restrict__ Cb2,
    ushort_t* __restrict__ Ct0, ushort_t* __restrict__ Ct1, ushort_t* __restrict__ Ct2,
    float alpha) {
  const int K = 1024;
  __shared__ __bf16 As[64][40];
  __shared__ __bf16 Bs[64][40];
  int tid = threadIdx.x;
  int m0 = blockIdx.y * 64, n0 = blockIdx.x * 64;

  const ushort_t* Bsel = B0;
  ushort_t* Cbz = Cb0;
  ushort_t* Ctz = Ct0;
  if (MODE == 0) {
    int z = blockIdx.z;
    Bsel = (z == 0) ? B0 : (z == 1) ? B1 : B2;
    Cbz = (z == 0) ? Cb0 : (z == 1) ? Cb1 : Cb2;
    Ctz = (z == 0) ? Ct0 : (z == 1) ? Ct1 : Ct2;
  }

  int lane = tid & 63, wave = tid >> 6;
  int wrow = wave >> 1, wcol = wave & 1;
  int fr = lane & 15, q = lane >> 4;

  f32x4 acc[2][2] = {};

  int ar = tid >> 2, ac = (tid & 3) * 8;
  #pragma unroll 1
  for (int seg = 0; seg < NSEG; seg++) {
    const ushort_t* Aseg = (seg == 0) ? A0 : (seg == 1) ? A1 : A2;
    const ushort_t* Bseg = (MODE == 0) ? Bsel : ((seg == 0) ? B0 : (seg == 1) ? B1 : B2);
    const ushort_t* Ag = Aseg + (size_t)(m0 + ar) * K + ac;
    const ushort_t* Bg = Bseg + (size_t)(n0 + ar) * K + ac;
    for (int k0 = 0; k0 < K; k0 += 32) {
      uint4 av = *(const uint4*)(Ag + k0);
      uint4 bv = *(const uint4*)(Bg + k0);
      __syncthreads();
      *(uint4*)&As[ar][ac] = av;
      *(uint4*)&Bs[ar][ac] = bv;
      __syncthreads();
      bf16x8 a0 = *(const bf16x8*)&As[wrow * 32 + fr][q * 8];
      bf16x8 a1 = *(const bf16x8*)&As[wrow * 32 + 16 + fr][q * 8];
      bf16x8 b0 = *(const bf16x8*)&Bs[wcol * 32 + fr][q * 8];
      bf16x8 b1 = *(const bf16x8*)&Bs[wcol * 32 + 16 + fr][q * 8];
      acc[0][0] = __builtin_amdgcn_mfma_f32_16x16x32_bf16(a0, b0, acc[0][0], 0, 0, 0);
      acc[0][1] = __builtin_amdgcn_mfma_f32_16x16x32_bf16(a0, b1, acc[0][1], 0, 0, 0);
      acc[1][0] = __builtin_amdgcn_mfma_f32_16x16x32_bf16(a1, b0, acc[1][0], 0, 0, 0);
      acc[1][1] = __builtin_amdgcn_mfma_f32_16x16x32_bf16(a1, b1, acc[1][1], 0, 0, 0);
    }
  }

  // C/D layout: col = lane&15, row = (lane>>4)*4 + reg
  #pragma unroll
  for (int mi = 0; mi < 2; mi++)
    #pragma unroll
    for (int ni = 0; ni < 2; ni++) {
      int col = n0 + wcol * 32 + ni * 16 + fr;
      int row0 = m0 + wrow * 32 + mi * 16 + q * 4;
      ushort_t pk[4];
      #pragma unroll
      for (int r = 0; r < 4; r++) {
        size_t idx = (size_t)(row0 + r) * E_DIM + col;
        float v = acc[mi][ni][r];
        if (MODE == 0) {
          ushort_t bu = f2bu(v);
          pk[r] = bu;
          Cbz[idx] = bu;
        } else if (MODE == 1) {
          Cb0[idx] = f2bu(T[idx] - v);
        } else {
          float nv = Cf[idx] + alpha * v;
          Cf[idx] = nv;
          Cb0[idx] = f2bu(nv);
        }
      }
      if (MODE == 0) {
        int hh = col >> 6, dd = col & 63;
        int bb = row0 >> 10, ss = row0 & 1023;
        *(uint2*)(Ctz + ((size_t)((bb * NH + hh) * HD + dd)) * S_LEN + ss) = *(uint2*)pk;
      }
    }
}

// ====================== MFMA attention, LDS-staged ======================

// ---- fused fwd: single-pass flash, online softmax; emits m, 1/l, g=O-Xs (bf16 + transposed), Dv ----
// grid (bh=32, y=16); pairing (16-y)+(y+1)=17 units/CU under in-order round-robin.
__global__ __launch_bounds__(256) void fwd_fused(const ushort_t* __restrict__ Qg,
                                                 const ushort_t* __restrict__ Kg,
                                                 const ushort_t* __restrict__ Vt,
                                                 const float* __restrict__ Xs,
                                                 float* __restrict__ mbuf,
                                                 float* __restrict__ lbuf,
                                                 ushort_t* __restrict__ Gb,
                                                 ushort_t* __restrict__ Gt,
                                                 float* __restrict__ Dv) {
  int bh = blockIdx.x, y = blockIdx.y;
  int it = (y < 8) ? (15 - y) : (y - 8);
  int b = bh >> 4, h = bh & 15;
  int tid = threadIdx.x, lane = tid & 63, wv = tid >> 6;
  int fr = lane & 15, q = lane >> 4;
  int i0 = it * 64, band = wv * 16;
  __shared__ ushort_t Kts[64][72];  // [j][d]
  __shared__ ushort_t Vts[64][72];  // [d][j]
  __shared__ ushort_t Ps[64][72];   // [i][j] wave-private bands

  const ushort_t* Qrow = Qg + (size_t)(b * S_LEN + i0 + band + fr) * E_DIM + h * HD;
  bf16x8 aq0 = ldg8(Qrow + q * 8);
  bf16x8 aq1 = ldg8(Qrow + 32 + q * 8);

  float m[4], l[4];
  #pragma unroll
  for (int r = 0; r < 4; r++) { m[r] = -1e30f; l[r] = 0.f; }
  f32x4 oacc[4] = {};

  #pragma unroll 1
  for (int jt = 0; jt <= it; jt++) {
    int j0 = jt * 64;
    __syncthreads();
    #pragma unroll
    for (int t = 0; t < 2; t++) {
      int u = tid + 256 * t;
      int r = u >> 3, c8 = (u & 7) * 8;
      *(uint4*)&Kts[r][c8] = *(const uint4*)(Kg + (size_t)(b * S_LEN + j0 + r) * E_DIM + h * HD + c8);
      *(uint4*)&Vts[r][c8] = *(const uint4*)(Vt + (size_t)(bh * HD + r) * S_LEN + j0 + c8);
    }
    __syncthreads();
    f32x4 sA[4];
    #pragma unroll
    for (int nc = 0; nc < 4; nc++) {
      bf16x8 bk0 = *(const bf16x8*)&Kts[nc * 16 + fr][q * 8];
      bf16x8 bk1 = *(const bf16x8*)&Kts[nc * 16 + fr][32 + q * 8];
      f32x4 z = {};
      z = __builtin_amdgcn_mfma_f32_16x16x32_bf16(aq0, bk0, z, 0, 0, 0);
      sA[nc] = __builtin_amdgcn_mfma_f32_16x16x32_bf16(aq1, bk1, z, 0, 0, 0);
    }
    float sv[4][4];
    #pragma unroll
    for (int nc = 0; nc < 4; nc++)
      #pragma unroll
      for (int r = 0; r < 4; r++) {
        int row = i0 + band + q * 4 + r;
        int col = j0 + nc * 16 + fr;
        sv[nc][r] = (col <= row) ? sA[nc][r] * SC_C : -1e30f;
      }
    #pragma unroll
    for (int r = 0; r < 4; r++) {
      float mx = fmaxf(fmaxf(sv[0][r], sv[1][r]), fmaxf(sv[2][r], sv[3][r]));
      #pragma unroll
      for (int off = 1; off < 16; off <<= 1) mx = fmaxf(mx, __shfl_xor(mx, off, 64));
      float mn = fmaxf(m[r], mx);
      float alpha = __expf(m[r] - mn);
      float ps = 0.f;
      #pragma unroll
      for (int nc = 0; nc < 4; nc++) {
        float p = __expf(sv[nc][r] - mn);
        Ps[band + q * 4 + r][nc * 16 + fr] = f2bu(p);
        ps += p;
      }
      #pragma unroll
      for (int off = 1; off < 16; off <<= 1) ps += __shfl_xor(ps, off, 64);
      l[r] = l[r] * alpha + ps;
      m[r] = mn;
      #pragma unroll
      for (int nc = 0; nc < 4; nc++) oacc[nc][r] *= alpha;
    }
    bf16x8 ap0 = *(const bf16x8*)&Ps[band + fr][q * 8];
    bf16x8 ap1 = *(const bf16x8*)&Ps[band + fr][32 + q * 8];
    #pragma unroll
    for (int nc = 0; nc < 4; nc++) {
      bf16x8 bv0 = *(const bf16x8*)&Vts[nc * 16 + fr][q * 8];
      bf16x8 bv1 = *(const bf16x8*)&Vts[nc * 16 + fr][32 + q * 8];
      oacc[nc] = __builtin_amdgcn_mfma_f32_16x16x32_bf16(ap0, bv0, oacc[nc], 0, 0, 0);
      oacc[nc] = __builtin_amdgcn_mfma_f32_16x16x32_bf16(ap1, bv1, oacc[nc], 0, 0, 0);
    }
  }
  // epilogue: g = O - Xs (bf16 normal + transposed), Dv partials
  float linv[4];
  #pragma unroll
  for (int r = 0; r < 4; r++) linv[r] = 1.0f / l[r];
  float dpart[4] = {};
  #pragma unroll
  for (int nc = 0; nc < 4; nc++) {
    ushort_t pg[4];
    #pragma unroll
    for (int r = 0; r < 4; r++) {
      int row = i0 + band + q * 4 + r;
      size_t gi = (size_t)(b * S_LEN + row) * E_DIM + h * HD + nc * 16 + fr;
      float o = oacc[nc][r] * linv[r];
      float g = o - Xs[gi];
      ushort_t bu = f2bu(g);
      Gb[gi] = bu;
      pg[r] = bu;
      dpart[r] += g * o;
    }
    int d = nc * 16 + fr;
    int s0 = i0 + band + q * 4;
    *(uint2*)(Gt + ((size_t)bh * HD + d) * S_LEN + s0) = *(uint2*)pg;
  }
  #pragma unroll
  for (int r = 0; r < 4; r++) {
    #pragma unroll
    for (int off = 1; off < 16; off <<= 1) dpart[r] += __shfl_xor(dpart[r], off, 64);
  }
  if (fr == 0) {
    #pragma unroll
    for (int r = 0; r < 4; r++) {
      size_t sid = (size_t)bh * S_LEN + i0 + band + q * 4 + r;
      mbuf[sid] = m[r];
      lbuf[sid] = linv[r];
      Dv[sid] = dpart[r];
    }
  }
}

// ---- merged backward: block (bh, y) does dq for i-tile y (y+1 tiles) THEN dk/dv for
//      j-tile y (16-y tiles) = exactly 17 work-units per block (perfect balance). ----
__global__ __launch_bounds__(256) void bwd_fused(const ushort_t* __restrict__ Qg,
                                                 const ushort_t* __restrict__ Kg,
                                                 const ushort_t* __restrict__ Vg,
                                                 const ushort_t* __restrict__ Gg,
                                                 const ushort_t* __restrict__ Qt,
                                                 const ushort_t* __restrict__ Kt,
                                                 const ushort_t* __restrict__ Gt,
                                                 const float* __restrict__ mbuf,
                                                 const float* __restrict__ lbuf,
                                                 const float* __restrict__ Dv,
                                                 ushort_t* __restrict__ GQ,
                                                 ushort_t* __restrict__ GK,
                                                 ushort_t* __restrict__ GV) {
  int bh = blockIdx.x, y = blockIdx.y;
  int b = bh >> 4, h = bh & 15;
  int tid = threadIdx.x, lane = tid & 63, wv = tid >> 6;
  int fr = lane & 15, q = lane >> 4;
  int band = wv * 16;
  __shared__ ushort_t smem[6][64][72];  // aliased across phases

  // ================= phase A: dq for i-tile y =================
  {
    ushort_t (*Kts)[72] = smem[0];  // [j][d]
    ushort_t (*Vts)[72] = smem[1];  // [j][d]
    ushort_t (*Ktt)[72] = smem[2];  // [d][j]
    ushort_t (*dSs)[72] = smem[3];
    int it = y, i0 = it * 64;

    const ushort_t* Qrow = Qg + (size_t)(b * S_LEN + i0 + band + fr) * E_DIM + h * HD;
    const ushort_t* Grow = Gg + (size_t)(b * S_LEN + i0 + band + fr) * E_DIM + h * HD;
    bf16x8 aq0 = ldg8(Qrow + q * 8), aq1 = ldg8(Qrow + 32 + q * 8);
    bf16x8 ag0 = ldg8(Grow + q * 8), ag1 = ldg8(Grow + 32 + q * 8);

    float mrow[4], linv[4], Dr[4];
    #pragma unroll
    for (int r = 0; r < 4; r++) {
      size_t sid = (size_t)bh * S_LEN + i0 + band + q * 4 + r;
      mrow[r] = mbuf[sid]; linv[r] = lbuf[sid]; Dr[r] = Dv[sid];
    }
    f32x4 dqacc[4] = {};

    #pragma unroll 1
    for (int jt = 0; jt <= it; jt++) {
      int j0 = jt * 64;
      __syncthreads();
      #pragma unroll
      for (int t = 0; t < 2; t++) {
        int u = tid + 256 * t;
        int r = u >> 3, c8 = (u & 7) * 8;
        *(uint4*)&Kts[r][c8] = *(const uint4*)(Kg + (size_t)(b * S_LEN + j0 + r) * E_DIM + h * HD + c8);
        *(uint4*)&Vts[r][c8] = *(const uint4*)(Vg + (size_t)(b * S_LEN + j0 + r) * E_DIM + h * HD + c8);
        *(uint4*)&Ktt[r][c8] = *(const uint4*)(Kt + (size_t)(bh * HD + r) * S_LEN + j0 + c8);
      }
      __syncthreads();
      f32x4 sA[4], dpA[4];
      #pragma unroll
      for (int nc = 0; nc < 4; nc++) {
        bf16x8 bk0 = *(const bf16x8*)&Kts[nc * 16 + fr][q * 8];
        bf16x8 bk1 = *(const bf16x8*)&Kts[nc * 16 + fr][32 + q * 8];
        bf16x8 bv0 = *(const bf16x8*)&Vts[nc * 16 + fr][q * 8];
        bf16x8 bv1 = *(const bf16x8*)&Vts[nc * 16 + fr][32 + q * 8];
        f32x4 z = {};
        z = __builtin_amdgcn_mfma_f32_16x16x32_bf16(aq0, bk0, z, 0, 0, 0);
        sA[nc] = __builtin_amdgcn_mfma_f32_16x16x32_bf16(aq1, bk1, z, 0, 0, 0);
        f32x4 z2 = {};
        z2 = __builtin_amdgcn_mfma_f32_16x16x32_bf16(ag0, bv0, z2, 0, 0, 0);
        dpA[nc] = __builtin_amdgcn_mfma_f32_16x16x32_bf16(ag1, bv1, z2, 0, 0, 0);
      }
      #pragma unroll
      for (int nc = 0; nc < 4; nc++)
        #pragma unroll
        for (int r = 0; r < 4; r++) {
          int row = i0 + band + q * 4 + r;
          int col = j0 + nc * 16 + fr;
          float ds = 0.f;
          if (col <= row) {
            float P = __expf(sA[nc][r] * SC_C - mrow[r]) * linv[r];
            ds = P * (dpA[nc][r] - Dr[r]) * SC_C;
          }
          dSs[band + q * 4 + r][nc * 16 + fr] = f2bu(ds);  // wave-private
        }
      bf16x8 ad0 = *(const bf16x8*)&dSs[band + fr][q * 8];
      bf16x8 ad1 = *(const bf16x8*)&dSs[band + fr][32 + q * 8];
      #pragma unroll
      for (int nc = 0; nc < 4; nc++) {
        bf16x8 bt0 = *(const bf16x8*)&Ktt[nc * 16 + fr][q * 8];
        bf16x8 bt1 = *(const bf16x8*)&Ktt[nc * 16 + fr][32 + q * 8];
        dqacc[nc] = __builtin_amdgcn_mfma_f32_16x16x32_bf16(ad0, bt0, dqacc[nc], 0, 0, 0);
        dqacc[nc] = __builtin_amdgcn_mfma_f32_16x16x32_bf16(ad1, bt1, dqacc[nc], 0, 0, 0);
      }
    }
    #pragma unroll
    for (int nc = 0; nc < 4; nc++)
      #pragma unroll
      for (int r = 0; r < 4; r++) {
        int row = i0 + band + q * 4 + r;
        size_t gi = (size_t)(b * S_LEN + row) * E_DIM + h * HD + nc * 16 + fr;
        GQ[gi] = f2bu(dqacc[nc][r]);
      }
  }

  // ================= phase B: dk/dv for j-tile y =================
  {
    ushort_t (*Qs_)[72] = smem[0];  // [i][d]
    ushort_t (*Gs_)[72] = smem[1];  // [i][d]
    ushort_t (*Qtt)[72] = smem[2];  // [d][i]
    ushort_t (*Gtt)[72] = smem[3];  // [d][i]
    ushort_t (*PT)[72]  = smem[4];  // [j][i]
    ushort_t (*dST)[72] = smem[5];  // [j][i]
    int jt = y, j0 = jt * 64;

    const ushort_t* Krow = Kg + (size_t)(b * S_LEN + j0 + band + fr) * E_DIM + h * HD;
    const ushort_t* Vrow = Vg + (size_t)(b * S_LEN + j0 + band + fr) * E_DIM + h * HD;
    bf16x8 ak0 = ldg8(Krow + q * 8), ak1 = ldg8(Krow + 32 + q * 8);
    bf16x8 av0 = ldg8(Vrow + q * 8), av1 = ldg8(Vrow + 32 + q * 8);

    f32x4 dkacc[4] = {}, dvacc[4] = {};

    #pragma unroll 1
    for (int i_t = jt; i_t < 16; i_t++) {
      int i0 = i_t * 64;
      __syncthreads();  // also protects phase-A's last LDS reads on first iteration
      #pragma unroll
      for (int t = 0; t < 2; t++) {
        int u = tid + 256 * t;
        int r = u >> 3, c8 = (u & 7) * 8;
        *(uint4*)&Qs_[r][c8] = *(const uint4*)(Qg + (size_t)(b * S_LEN + i0 + r) * E_DIM + h * HD + c8);
        *(uint4*)&Gs_[r][c8] = *(const uint4*)(Gg + (size_t)(b * S_LEN + i0 + r) * E_DIM + h * HD + c8);
        *(uint4*)&Qtt[r][c8] = *(const uint4*)(Qt + (size_t)(bh * HD + r) * S_LEN + i0 + c8);
        *(uint4*)&Gtt[r][c8] = *(const uint4*)(Gt + (size_t)(bh * HD + r) * S_LEN + i0 + c8);
      }
      __syncthreads();
      float mc[4], lc[4], Dc[4];
      #pragma unroll
      for (int nc = 0; nc < 4; nc++) {
        size_t sid = (size_t)bh * S_LEN + i0 + nc * 16 + fr;
        mc[nc] = mbuf[sid]; lc[nc] = lbuf[sid]; Dc[nc] = Dv[sid];
      }
      f32x4 stA[4], dptA[4];
      #pragma unroll
      for (int nc = 0; nc < 4; nc++) {
        bf16x8 bq0 = *(const bf16x8*)&Qs_[nc * 16 + fr][q * 8];
        bf16x8 bq1 = *(const bf16x8*)&Qs_[nc * 16 + fr][32 + q * 8];
        bf16x8 bg0 = *(const bf16x8*)&Gs_[nc * 16 + fr][q * 8];
        bf16x8 bg1 = *(const bf16x8*)&Gs_[nc * 16 + fr][32 + q * 8];
        f32x4 z = {};
        z = __builtin_amdgcn_mfma_f32_16x16x32_bf16(ak0, bq0, z, 0, 0, 0);
        stA[nc] = __builtin_amdgcn_mfma_f32_16x16x32_bf16(ak1, bq1, z, 0, 0, 0);
        f32x4 z2 = {};
        z2 = __builtin_amdgcn_mfma_f32_16x16x32_bf16(av0, bg0, z2, 0, 0, 0);
        dptA[nc] = __builtin_amdgcn_mfma_f32_16x16x32_bf16(av1, bg1, z2, 0, 0, 0);
      }
      #pragma unroll
      for (int nc = 0; nc < 4; nc++)
        #pragma unroll
        for (int r = 0; r < 4; r++) {
          int jrow = j0 + band + q * 4 + r;
          int icol = i0 + nc * 16 + fr;
          float P = 0.f, ds = 0.f;
          if (icol >= jrow) {
            P = __expf(stA[nc][r] * SC_C - mc[nc]) * lc[nc];
            ds = P * (dptA[nc][r] - Dc[nc]) * SC_C;
          }
          PT[band + q * 4 + r][nc * 16 + fr] = f2bu(P);   // wave-private
          dST[band + q * 4 + r][nc * 16 + fr] = f2bu(ds);
        }
      bf16x8 ap0 = *(const bf16x8*)&PT[band + fr][q * 8];
      bf16x8 ap1 = *(const bf16x8*)&PT[band + fr][32 + q * 8];
      bf16x8 ad0 = *(const bf16x8*)&dST[band + fr][q * 8];
      bf16x8 ad1 = *(const bf16x8*)&dST[band + fr][32 + q * 8];
      #pragma unroll
      for (int nc = 0; nc < 4; nc++) {
        bf16x8 bg0 = *(const bf16x8*)&Gtt[nc * 16 + fr][q * 8];
        bf16x8 bg1 = *(const bf16x8*)&Gtt[nc * 16 + fr][32 + q * 8];
        bf16x8 bq0 = *(const bf16x8*)&Qtt[nc * 16 + fr][q * 8];
        bf16x8 bq1 = *(const bf16x8*)&Qtt[nc * 16 + fr][32 + q * 8];
        dvacc[nc] = __builtin_amdgcn_mfma_f32_16x16x32_bf16(ap0, bg0, dvacc[nc], 0, 0, 0);
        dvacc[nc] = __builtin_amdgcn_mfma_f32_16x16x32_bf16(ap1, bg1, dvacc[nc], 0, 0, 0);
        dkacc[nc] = __builtin_amdgcn_mfma_f32_16x16x32_bf16(ad0, bq0, dkacc[nc], 0, 0, 0);
        dkacc[nc] = __builtin_amdgcn_mfma_f32_16x16x32_bf16(ad1, bq1, dkacc[nc], 0, 0, 0);
      }
    }
    #pragma unroll
    for (int nc = 0; nc < 4; nc++)
      #pragma unroll
      for (int r = 0; r < 4; r++) {
        int jrow = j0 + band + q * 4 + r;
        size_t gi = (size_t)(b * S_LEN + jrow) * E_DIM + h * HD + nc * 16 + fr;
        GK[gi] = f2bu(dkacc[nc][r]);
        GV[gi] = f2bu(dvacc[nc][r]);
      }
  }
}

// ---------------- launch ----------------
extern "C" void kernel_launch(void* const* d_in, const int* in_sizes, int n_in,
                              void* d_out, int out_size, void* d_ws, size_t ws_size,
                              hipStream_t stream) {
  const float* T1 = (const float*)d_in[0];
  const float* Wq = (const float*)d_in[1];
  const float* Wk = (const float*)d_in[2];
  const float* Wv = (const float*)d_in[3];
  const float* Wo = (const float*)d_in[4];

  const size_t M2 = 2097152;   // 2048*1024
  const size_t M1 = 1048576;
  float* w = (float*)d_ws;
  float* Xs = w;                       // 8 MB fp32 target
  float* mS = Xs + M2;                 // 64K f32
  float* lS = mS + 65536;
  float* DvS = lS + 65536;
  ushort_t* u = (ushort_t*)(DvS + 65536);
  ushort_t* W0 = u;          ushort_t* W1 = W0 + M1;  ushort_t* W2 = W1 + M1;
  ushort_t* W3 = W2 + M1;    ushort_t* W4 = W3 + M1;  ushort_t* W5 = W4 + M1;
  ushort_t* Qb = W5 + M1;    ushort_t* Kb = Qb + M2;  ushort_t* Vb = Kb + M2;
  ushort_t* Qt = Vb + M2;    ushort_t* Kt = Qt + M2;  ushort_t* Vt = Kt + M2;
  ushort_t* Gt = Vt + M2;
  ushort_t* Gb = Gt + M2;
  ushort_t* GQb = Gb + M2;   ushort_t* GKb = GQb + M2; ushort_t* GVb = GKb + M2;
  ushort_t* X2b = GVb + M2;
  ushort_t* Rb = GQb;        // stage-1 aliases
  ushort_t* Xsb = GKb;
  float* X2 = (float*)d_out;

  hipMemsetAsync(Xs, 0, M2 * sizeof(float), stream);
  hipMemsetAsync(Xsb, 0, M2 * sizeof(ushort_t), stream);
  hipMemsetAsync(X2, 0, M2 * sizeof(float), stream);
  hipMemsetAsync(X2b, 0, M2 * sizeof(ushort_t), stream);

  dim3 pgrid(16, 16);
  dim3 ggrid(16, 32);       // 64x64 tiles -> 512 blocks = 2/CU
  dim3 ggrid3(16, 32, 3);   // QKV: 1536 blocks = 6/CU
  dim3 agrid(BH_CNT, 16);   // attention: (bh, y)

  // ---- stage 1 ----
  prep_w<<<pgrid, 256, 0, stream>>>(Wo, W0, W1);
  for (int t = 0; t < 3; t++) {
    gemm_mf<1, 1><<<ggrid, 256, 0, stream>>>(Xsb, nullptr, nullptr, W0, nullptr, nullptr,
                                             nullptr, T1, Rb, nullptr, nullptr,
                                             nullptr, nullptr, nullptr, 0.f);
    gemm_mf<2, 1><<<ggrid, 256, 0, stream>>>(Rb, nullptr, nullptr, W1, nullptr, nullptr,
                                             Xs, nullptr, Xsb, nullptr, nullptr,
                                             nullptr, nullptr, nullptr, LR_C);
  }
  prep_w<<<pgrid, 256, 0, stream>>>(Wq, W0, W3);
  prep_w<<<pgrid, 256, 0, stream>>>(Wk, W1, W4);
  prep_w<<<pgrid, 256, 0, stream>>>(Wv, W2, W5);

  // ---- stage 2 ----
  for (int t = 0; t < 3; t++) {
    gemm_mf<0, 1><<<ggrid3, 256, 0, stream>>>(X2b, nullptr, nullptr, W0, W1, W2,
                                              nullptr, nullptr, Qb, Kb, Vb,
                                              Qt, Kt, Vt, 0.f);
    fwd_fused<<<agrid, 256, 0, stream>>>(Qb, Kb, Vt, Xs, mS, lS, Gb, Gt, DvS);
    bwd_fused<<<agrid, 256, 0, stream>>>(Qb, Kb, Vb, Gb, Qt, Kt, Gt, mS, lS, DvS,
                                         GQb, GKb, GVb);
    gemm_mf<2, 3><<<ggrid, 256, 0, stream>>>(GQb, GKb, GVb, W3, W4, W5,
                                             X2, nullptr, X2b, nullptr, nullptr,
                                             nullptr, nullptr, nullptr, -LR_C);
  }
}